// Round 5
// baseline (5308.316 us; speedup 1.0000x reference)
//
#include <hip/hip_runtime.h>
#include <math.h>

// ---------------- problem constants ----------------
#define ATOT 261888          // sum over levels of H*W*3
#define MCAND 21840          // 6000+6000+6000+3072+768 candidates per image
#define POSTK 1000
#define CMB (2*ATOT*5)       // combined output floats = 2618880
#define KB_OFF CMB           // keep_boxes offset in d_out
#define KS_OFF (CMB+8000)    // keep_scores
#define KV_OFF (CMB+10000)   // valid
#define SCALE_CLAMP 4.135166556742356f
#define RCAP 4096

typedef unsigned long long u64;

// ---------------- fallback (small-ws) layout, float units ----------------
#define WS_T   0
#define WS_SC  (256*65536)
#define WS_CB  (WS_SC + 2*ATOT)
#define WS_CS  (WS_CB + 2*MCAND*4)
#define WS_CTL (WS_CS + 2*MCAND)

// ctl indices (u32)
#define C_PRE 0
#define C_KCUR 6
#define C_CNT 12
#define C_TIE 18
#define N_THRPREV 24
#define N_KEPT 26
#define N_DONE 28
#define N_SCNT 30
#define N_LAST 32
#define C_GH 40
#define C_TIEIDX (C_GH + 6*256)
#define CTL_SIZE (C_TIEIDX + 6*1024)
#define WS_WP  (WS_CTL + CTL_SIZE)

// ---------------- fused (big-ws) layout, float units ----------------
#define FT_T   0
#define FT_TSZ 22347776                 // 256 * 87296 (all levels, one image)
#define FT_SC  22347776
#define FT_CB  (FT_SC + 2*ATOT)         // 22871552
#define FT_CS  (FT_CB + 2*MCAND*4)      // 23046272
#define FT_CTL (FT_CS + 2*MCAND)        // 23089952
#define FT_WP  (FT_CTL + CTL_SIZE)      // 23097672
#define FT_END (FT_WP + 589824)         // 23687496 floats = 94,749,984 B

// ---- NMS scratch inside the (dead-by-then) t buffer ----
#define NS_KEY  0
#define NS_BOX  16384
#define NS_AREA 49152
#define NS_DIAG 57344
#define NS_PSUP 73728
#define NS_KBOX 73984
#define NS_MASK 84224                   // end 1,132,800 floats

__device__ const int LW[5]    = {256,128,64,32,16};
__device__ const int LM[5]    = {196608,49152,12288,3072,768};
__device__ const int LBASE[5] = {0,196608,245760,258048,261120};
__device__ const int LSTR[5]  = {4,8,16,32,64};
__device__ const int LSZ[5]   = {32,64,128,256,512};
__device__ const int CBASE[5] = {0,6000,12000,18000,21072};
__device__ const int TOFF[5]  = {0,16777216,20971520,22020096,22282240}; // 256*cumHW

__device__ inline unsigned fkey(float f) {
  unsigned u = __float_as_uint(f);
  return u ^ (unsigned)(((int)u >> 31) | 0x80000000);
}
__device__ inline float unfkey(unsigned k) {
  unsigned u = (k & 0x80000000u) ? (k ^ 0x80000000u) : ~k;
  return __uint_as_float(u);
}
__device__ inline int lvl_of(int idx) {
  return idx < 6000 ? 0 : idx < 12000 ? 1 : idx < 18000 ? 2 : idx < 21072 ? 3 : 4;
}
__device__ inline float iou_f(float ax1,float ay1,float ax2,float ay2,float aar,
                              float bx1,float by1,float bx2,float by2,float bar) {
  float ix1 = fmaxf(ax1,bx1), iy1 = fmaxf(ay1,by1);
  float ix2 = fminf(ax2,bx2), iy2 = fminf(ay2,by2);
  float inter = fmaxf(ix2-ix1,0.f) * fmaxf(iy2-iy1,0.f);
  return inter / (aar + bar - inter + 1e-9f);
}

// =========================================================================
// MFMA conv: f16 hi/lo split (inputs & weights pre-scaled by 2^11; epilogue
// rescales by 2^-22). 3 MFMAs (hh, lh, hl) per nominal fp32 product.
// Big path: 682 blocks x 1024 threads (16 waves, 4/SIMD), 16x16 px tile,
// async-split staging (load-early/convert-late), conflict-free [ks][p][8]
// LDS layout, heads fused.
// =========================================================================
typedef _Float16 f16;
typedef _Float16 f16x2 __attribute__((ext_vector_type(2)));
typedef _Float16 f16x8 __attribute__((ext_vector_type(8)));
typedef float f32x4 __attribute__((ext_vector_type(4)));

#define MFMA16(a,b,c) __builtin_amdgcn_mfma_f32_16x16x32_f16(a,b,c,0,0,0)
#define AST 40            // fallback-path padded channel stride (f16)
#define WHALF 589824      // f16 elements per half (hi block / lo block)

// weight prep: conv_w[oc][ci][kh][kw] fp32 ->
//   wsp[h][t][kc][ks][oc][j] f16, h in {hi,lo}, ci = kc*32+ks*8+j, t = kh*3+kw
__global__ __launch_bounds__(256) void wprep_mfma(const float* __restrict__ wgt,
                                                  f16* __restrict__ wsp) {
  int o = blockIdx.x*256 + threadIdx.x;
  if (o >= WHALF) return;
  int j  = o & 7;
  int oc = (o >> 3) & 255;
  int ks = (o >> 11) & 3;
  int kc = (o >> 13) & 7;
  int t  = o >> 16;
  int ci = kc*32 + ks*8 + j;
  float v = wgt[(oc*256 + ci)*9 + t] * 2048.f;
  f16 hi = (f16)v;
  f16 lo = (f16)(v - (float)hi);
  wsp[o] = hi;
  wsp[WHALF + o] = lo;
}

// ---------------- BIG-TILE fused conv+heads -------------------------------
// LDS: 2 staging buffers x (Ah 10368 + Al 10368 f16) = 82,944 B + wHs 15,360.
// Layout: Ah[(ks*324 + p)*8 + j], ci = kc*32 + ks*8 + j -> b128 read & write
// at consecutive 16B per lane = bank-conflict-free.
#define NUNIT 1296        // 4 ks * 324 halo px
#define ABUF 10368        // f16 per Ah (or Al) block
#define SBUF2 20736       // f16 per full buffer (Ah+Al)

__global__ __launch_bounds__(1024,4) void conv_big(
    const float* __restrict__ f0, const float* __restrict__ f1,
    const float* __restrict__ f2, const float* __restrict__ f3,
    const float* __restrict__ f4, const f16* __restrict__ wsp,
    const float* __restrict__ bias,
    const float* __restrict__ ow, const float* __restrict__ obp,
    const float* __restrict__ dwp, const float* __restrict__ dbp,
    float* __restrict__ comb, float* __restrict__ scores) {
  __shared__ __align__(16) char SBc[82944];
  __shared__ float wHs[15][256];
  const int tid = threadIdx.x;

  // block geometry: id -> (image, level, tile). 341 blocks per image.
  int id = blockIdx.x;
  int n = (id >= 341) ? 1 : 0;
  int rem = id - n*341;
  int lvl, tile;
  if (rem < 256)      { lvl = 0; tile = rem; }
  else if (rem < 320) { lvl = 1; tile = rem - 256; }
  else if (rem < 336) { lvl = 2; tile = rem - 320; }
  else if (rem < 340) { lvl = 3; tile = rem - 336; }
  else                { lvl = 4; tile = 0; }
  const int W = LW[lvl], H = W, HW = W*W;
  const int tw = W >> 4;
  const int ty0 = tile / tw, tx0 = tile - ty0*tw;
  const int x0 = tx0*16, y0 = ty0*16;
  const int lbase = LBASE[lvl];
  const float* in = (lvl==0?f0:lvl==1?f1:lvl==2?f2:lvl==3?f3:f4) + (long)n*256*HW;

  const int wv   = tid >> 6;
  const int lane = tid & 63;
  const int l15  = lane & 15;
  const int ks   = lane >> 4;
  const int rg   = wv >> 3;      // row group: rows rg*8 .. rg*8+7
  const int cg   = wv & 7;       // oc slice:  oc cg*32 .. cg*32+31

  // stage head weights (consumed in epilogue, after many barriers)
  for (int i = tid; i < 768; i += 1024)  wHs[i>>8][i&255] = ow[i];
  for (int i = tid; i < 3072; i += 1024) wHs[3+(i>>8)][i&255] = dwp[i];

  // ---- per-thread staging geometry (loop-invariant over kc) ----
  // unit0 = tid (ks0*324+p0), unit1 = tid+1024 (ks=3, p=tid+52) if tid<272.
  int ks0 = tid / 324; int p0 = tid - ks0*324;
  int hy0 = p0/18, hx0 = p0 - hy0*18;
  int gy0 = y0 + hy0 - 1, gx0 = x0 + hx0 - 1;
  const bool okb0 = (gy0>=0) & (gy0<H) & (gx0>=0) & (gx0<W);
  const int boff0 = ks0*8*HW + min(max(gy0,0),H-1)*W + min(max(gx0,0),W-1);
  const bool has1 = tid < 272;
  int p1 = tid + 52;
  int hy1 = p1/18, hx1 = p1 - hy1*18;
  int gy1 = y0 + hy1 - 1, gx1 = x0 + hx1 - 1;
  const bool okb1 = (gy1>=0) & (gy1<H) & (gx1>=0) & (gx1<W);
  const int boff1 = 24*HW + min(max(gy1,0),H-1)*W + min(max(gx1,0),W-1);

  float sv0[8], sv1[8];
  auto stage_load = [&](int kc) {
    const float* q = in + (size_t)(kc*32)*HW;
    #pragma unroll
    for (int j = 0; j < 8; ++j) sv0[j] = q[boff0 + j*HW];
    if (has1) {
      #pragma unroll
      for (int j = 0; j < 8; ++j) sv1[j] = q[boff1 + j*HW];
    }
  };
  auto stage_write = [&](int b) {
    f16* AhB = (f16*)SBc + b*SBUF2;
    f16* AlB = AhB + ABUF;
    f16x8 vh, vl;
    #pragma unroll
    for (int j = 0; j < 8; ++j) {
      float v = okb0 ? sv0[j]*2048.f : 0.f;
      f16 h = (f16)v; vh[j] = h; vl[j] = (f16)(v - (float)h);
    }
    *(f16x8*)&AhB[tid*8] = vh;
    *(f16x8*)&AlB[tid*8] = vl;
    if (has1) {
      #pragma unroll
      for (int j = 0; j < 8; ++j) {
        float v = okb1 ? sv1[j]*2048.f : 0.f;
        f16 h = (f16)v; vh[j] = h; vl[j] = (f16)(v - (float)h);
      }
      *(f16x8*)&AhB[(1024+tid)*8] = vh;
      *(f16x8*)&AlB[(1024+tid)*8] = vl;
    }
  };

  const f32x4 vzero = {0.f, 0.f, 0.f, 0.f};
  f32x4 acc[8][2];
  #pragma unroll
  for (int mt = 0; mt < 8; ++mt) { acc[mt][0] = vzero; acc[mt][1] = vzero; }

  stage_load(0);
  stage_write(0);
  __syncthreads();

  for (int kc = 0; kc < 8; ++kc) {
    const int b = kc & 1;
    if (kc < 7) stage_load(kc + 1);      // loads in flight under MFMAs (T14)
    const f16* AhB = (const f16*)SBc + b*SBUF2;
    const f16* AlB = AhB + ABUF;
    for (int t = 0; t < 9; ++t) {
      const int tyk = t / 3, txk = t - (t/3)*3;
      const f16* wb = wsp + (((t*8 + kc)*4 + ks)*256 + cg*32 + l15)*8;
      f16x8 Bh0 = *(const f16x8*)(wb);
      f16x8 Bh1 = *(const f16x8*)(wb + 128);
      f16x8 Bl0 = *(const f16x8*)(wb + WHALF);
      f16x8 Bl1 = *(const f16x8*)(wb + WHALF + 128);
      #pragma unroll
      for (int mt = 0; mt < 8; ++mt) {
        const int p = (rg*8 + mt + tyk)*18 + l15 + txk;
        f16x8 Af = *(const f16x8*)&AhB[(ks*324 + p)*8];
        f16x8 Ae = *(const f16x8*)&AlB[(ks*324 + p)*8];
        acc[mt][0] = MFMA16(Af, Bh0, acc[mt][0]);
        acc[mt][1] = MFMA16(Af, Bh1, acc[mt][1]);
        acc[mt][0] = MFMA16(Ae, Bh0, acc[mt][0]);
        acc[mt][1] = MFMA16(Ae, Bh1, acc[mt][1]);
        acc[mt][0] = MFMA16(Af, Bl0, acc[mt][0]);
        acc[mt][1] = MFMA16(Af, Bl1, acc[mt][1]);
      }
    }
    if (kc < 7) stage_write(b ^ 1);      // convert late, other buffer
    __syncthreads();
  }

  // ---- fused heads epilogue (no t-buffer), 2 passes over j in LDS ----
  const float rs = 1.f / 4194304.f;      // 2^-22, exact
  float bb0 = bias[cg*32 + l15], bb1 = bias[cg*32 + 16 + l15];
  #pragma unroll
  for (int mt = 0; mt < 8; ++mt) {       // acc := relu(conv) in place
    f32x4 a0 = acc[mt][0], a1 = acc[mt][1];
    #pragma unroll
    for (int i = 0; i < 4; ++i) {
      a0[i] = fmaxf(a0[i]*rs + bb0, 0.f);
      a1[i] = fmaxf(a1[i]*rs + bb1, 0.f);
    }
    acc[mt][0] = a0; acc[mt][1] = a1;
  }

  float* part = (float*)SBc;             // staging dead; 16384 floats used
  #pragma unroll
  for (int h = 0; h < 2; ++h) {
    const int jb = h*8;
    #pragma unroll
    for (int mt = 0; mt < 8; ++mt) {
      #pragma unroll
      for (int jj = 0; jj < 8; ++jj) {
        const int j = jb + jj;
        if (j < 15) {
          float w0 = wHs[j][cg*32 + l15];
          float w1 = wHs[j][cg*32 + 16 + l15];
          f32x4 p4;
          #pragma unroll
          for (int i = 0; i < 4; ++i)
            p4[i] = acc[mt][0][i]*w0 + acc[mt][1][i]*w1;
          #pragma unroll
          for (int m = 1; m < 16; m <<= 1) {
            p4[0] += __shfl_xor(p4[0], m);
            p4[1] += __shfl_xor(p4[1], m);
            p4[2] += __shfl_xor(p4[2], m);
            p4[3] += __shfl_xor(p4[3], m);
          }
          if (l15 == 0) {
            float* pp = part + ((((cg*2 + rg)*8 + mt)*4 + ks)*8 + jj)*4;
            pp[0] = p4[0]; pp[1] = p4[1]; pp[2] = p4[2]; pp[3] = p4[3];
          }
        }
      }
    }
    __syncthreads();
    if (tid < 256) {
      int row16 = tid >> 4, xi = tid & 15;
      int rg2 = row16 >> 3, mt = row16 & 7;
      int k2 = xi >> 2, xj = xi & 3;
      int pos = (y0 + rg2*8 + mt)*W + x0 + xi;
      long base = (long)n*ATOT + lbase + (long)pos*3;
      #pragma unroll
      for (int jj = 0; jj < 8; ++jj) {
        const int j = jb + jj;
        if (j < 15) {
          float s = 0.f;
          #pragma unroll
          for (int c2 = 0; c2 < 8; ++c2)
            s += part[((((c2*2 + rg2)*8 + mt)*4 + k2)*8 + jj)*4 + xj];
          if (j < 3) {
            float lg = s + obp[j];
            comb[(base+j)*5] = lg;
            scores[(long)n*ATOT + lbase + pos*3 + j] = lg;
          } else {
            int a = (j-3) >> 2, q = (j-3) & 3;
            comb[(base+a)*5 + 1 + q] = s + dbp[j-3];
          }
        }
      }
    }
    __syncthreads();                     // protect part before pass 2
  }
}

// ---------------- fallback conv (small-ws): 16x8 tile, writes t ----------
__global__ __launch_bounds__(256,2) void conv_lvl_mfma(
    const float* __restrict__ in, const f16* __restrict__ wsp,
    const float* __restrict__ bias, float* __restrict__ outp, int H, int W) {
  __shared__ __align__(16) char SBc[28800];
  f16* Ah = (f16*)SBc;
  f16* Al = (f16*)(SBc + 14400);
  const int tid  = threadIdx.x;
  const int wv   = tid >> 6;
  const int lane = tid & 63;
  const int l15  = lane & 15;
  const int ks   = lane >> 4;
  const int HW   = H * W;
  const int x0 = blockIdx.x*16, y0 = blockIdx.y*8;

  const f32x4 vzero = {0.f, 0.f, 0.f, 0.f};
  f32x4 acc[8][4];
  #pragma unroll
  for (int mt = 0; mt < 8; ++mt)
    #pragma unroll
    for (int nt = 0; nt < 4; ++nt) acc[mt][nt] = vzero;

  for (int kc = 0; kc < 8; ++kc) {
    __syncthreads();
    for (int i = tid; i < 2880; i += 256) {
      int cp = i / 180; int p = i - cp*180;
      int hy = p / 18, hx = p - hy*18;
      int gy = y0 + hy - 1, gx = x0 + hx - 1;
      float v0 = 0.f, v1 = 0.f;
      if (gy >= 0 && gy < H && gx >= 0 && gx < W) {
        const float* q = in + (long)(kc*32 + 2*cp)*HW + gy*W + gx;
        v0 = q[0] * 2048.f;
        v1 = q[HW] * 2048.f;
      }
      f16 h0 = (f16)v0, h1 = (f16)v1;
      f16 e0 = (f16)(v0 - (float)h0), e1 = (f16)(v1 - (float)h1);
      f16x2 ph; ph[0] = h0; ph[1] = h1;
      f16x2 pl; pl[0] = e0; pl[1] = e1;
      *(f16x2*)&Ah[p*AST + 2*cp] = ph;
      *(f16x2*)&Al[p*AST + 2*cp] = pl;
    }
    __syncthreads();
    for (int t = 0; t < 9; ++t) {
      const int tyk = t / 3, txk = t - (t/3)*3;
      const f16* wb = wsp + (((t*8 + kc)*4 + ks)*256 + wv*64 + l15)*8;
      f16x8 Bh0 = *(const f16x8*)(wb);
      f16x8 Bh1 = *(const f16x8*)(wb + 128);
      f16x8 Bh2 = *(const f16x8*)(wb + 256);
      f16x8 Bh3 = *(const f16x8*)(wb + 384);
      f16x8 Bl0 = *(const f16x8*)(wb + WHALF);
      f16x8 Bl1 = *(const f16x8*)(wb + WHALF + 128);
      f16x8 Bl2 = *(const f16x8*)(wb + WHALF + 256);
      f16x8 Bl3 = *(const f16x8*)(wb + WHALF + 384);
      #pragma unroll
      for (int mt = 0; mt < 8; ++mt) {
        const int p = (mt + tyk)*18 + l15 + txk;
        f16x8 Af = *(const f16x8*)&Ah[p*AST + ks*8];
        f16x8 Ae = *(const f16x8*)&Al[p*AST + ks*8];
        acc[mt][0] = MFMA16(Af, Bh0, acc[mt][0]);
        acc[mt][1] = MFMA16(Af, Bh1, acc[mt][1]);
        acc[mt][2] = MFMA16(Af, Bh2, acc[mt][2]);
        acc[mt][3] = MFMA16(Af, Bh3, acc[mt][3]);
        acc[mt][0] = MFMA16(Ae, Bh0, acc[mt][0]);
        acc[mt][1] = MFMA16(Ae, Bh1, acc[mt][1]);
        acc[mt][2] = MFMA16(Ae, Bh2, acc[mt][2]);
        acc[mt][3] = MFMA16(Ae, Bh3, acc[mt][3]);
        acc[mt][0] = MFMA16(Af, Bl0, acc[mt][0]);
        acc[mt][1] = MFMA16(Af, Bl1, acc[mt][1]);
        acc[mt][2] = MFMA16(Af, Bl2, acc[mt][2]);
        acc[mt][3] = MFMA16(Af, Bl3, acc[mt][3]);
      }
    }
  }
  const float rs = 1.f / 4194304.f;
  #pragma unroll
  for (int nt = 0; nt < 4; ++nt) {
    int oc = wv*64 + nt*16 + l15;
    float bbv = bias[oc];
    #pragma unroll
    for (int mt = 0; mt < 8; ++mt) {
      f32x4 a = acc[mt][nt];
      float4 v;
      v.x = fmaxf(a[0]*rs + bbv, 0.f);
      v.y = fmaxf(a[1]*rs + bbv, 0.f);
      v.z = fmaxf(a[2]*rs + bbv, 0.f);
      v.w = fmaxf(a[3]*rs + bbv, 0.f);
      *(float4*)&outp[(long)oc*HW + (y0+mt)*W + x0 + ks*4] = v;
    }
  }
}

// ---------------- 1x1 heads (fallback path only) ----------------
__global__ __launch_bounds__(256) void heads1x1(
    const float* __restrict__ t, const float* __restrict__ ow, const float* __restrict__ ob,
    const float* __restrict__ dw, const float* __restrict__ db,
    float* __restrict__ comb, float* __restrict__ scores, int HW, int lbase, int n) {
  __shared__ float wS[15][256];
  const int tid = threadIdx.x;
  for (int i = tid; i < 3*256; i += 256) wS[i>>8][i&255] = ow[i];
  for (int i = tid; i < 12*256; i += 256) wS[3+(i>>8)][i&255] = dw[i];
  __syncthreads();
  int p0 = (blockIdx.x*256 + threadIdx.x)*4;
  if (p0 >= HW) return;
  float acc[15][4] = {};
  for (int c = 0; c < 256; ++c) {
    float4 v = *(const float4*)&t[c*HW + p0];
    float vv[4] = {v.x, v.y, v.z, v.w};
    #pragma unroll
    for (int k = 0; k < 15; ++k) {
      float w = wS[k][c];
      #pragma unroll
      for (int j = 0; j < 4; ++j) acc[k][j] += w * vv[j];
    }
  }
  float obv[3]; for (int i2 = 0; i2 < 3; ++i2) obv[i2] = ob[i2];
  float dbv[12]; for (int i2 = 0; i2 < 12; ++i2) dbv[i2] = db[i2];
  for (int j = 0; j < 4; ++j) {
    int pos = p0 + j;
    long base = (long)n*ATOT + lbase + (long)pos*3;
    #pragma unroll
    for (int a = 0; a < 3; ++a) {
      float lg = acc[a][j] + obv[a];
      comb[(base+a)*5] = lg;
      scores[(long)n*ATOT + lbase + pos*3 + a] = lg;
      #pragma unroll
      for (int q = 0; q < 4; ++q)
        comb[(base+a)*5 + 1 + q] = acc[3 + a*4 + q][j] + dbv[a*4+q];
    }
  }
}

// ---------------- decode ----------------
__device__ void decode_store(int n, int lvl, int idx, int slot,
                             const float* comb, float* cboxes, float* cscores) {
  int W = LW[lvl];
  int a = idx % 3; int p = idx / 3;
  int wx = p % W, hy = p / W;
  double r = (a == 0) ? 0.5 : (a == 1) ? 1.0 : 2.0;
  double sz = (double)LSZ[lvl];
  double wsd = sqrt(sz*sz/r);
  double hsd = wsd * r;
  double cxd = (double)(wx * LSTR[lvl]);
  double cyd = (double)(hy * LSTR[lvl]);
  float ax1 = (float)(cxd - 0.5*wsd), ay1 = (float)(cyd - 0.5*hsd);
  float ax2 = (float)(cxd + 0.5*wsd), ay2 = (float)(cyd + 0.5*hsd);
  float aw = ax2 - ax1, ah = ay2 - ay1;
  float acx = ax1 + 0.5f*aw, acy = ay1 + 0.5f*ah;
  long g = (long)n*ATOT + LBASE[lvl] + idx;
  const float* cm = comb + g*5;
  float sc = cm[0];
  float dx = cm[1], dy = cm[2], dwv = cm[3], dhv = cm[4];
  dwv = fminf(dwv, SCALE_CLAMP); dhv = fminf(dhv, SCALE_CLAMP);
  float pcx = __fadd_rn(__fmul_rn(dx, aw), acx);
  float pcy = __fadd_rn(__fmul_rn(dy, ah), acy);
  float pw = __fmul_rn(expf(dwv), aw);
  float ph = __fmul_rn(expf(dhv), ah);
  float x1 = __fsub_rn(pcx, 0.5f*pw), y1 = __fsub_rn(pcy, 0.5f*ph);
  float x2 = __fadd_rn(pcx, 0.5f*pw), y2 = __fadd_rn(pcy, 0.5f*ph);
  x1 = fminf(fmaxf(x1, 0.f), 1024.f);
  y1 = fminf(fmaxf(y1, 0.f), 1024.f);
  x2 = fminf(fmaxf(x2, 0.f), 1024.f);
  y2 = fminf(fmaxf(y2, 0.f), 1024.f);
  float* cbp = cboxes + ((long)n*MCAND + slot)*4;
  cbp[0]=x1; cbp[1]=y1; cbp[2]=x2; cbp[3]=y2;
  cscores[(long)n*MCAND + slot] = sc;
}

// ---------------- top-k kernels ----------------
__global__ void init_ctl(unsigned* ctl) {
  for (int i = threadIdx.x; i < CTL_SIZE; i += 256) ctl[i] = 0;
  __syncthreads();
  if (threadIdx.x < 6) ctl[C_KCUR + threadIdx.x] = 6000;
  if (threadIdx.x < 2) ctl[N_THRPREV + threadIdx.x] = 0xFFFFFFFFu;
}

__global__ __launch_bounds__(256) void tk_hist(const float* __restrict__ scores,
                                               unsigned* ctl, int pass) {
  int t = blockIdx.y; int lvl = t >> 1, n = t & 1;
  int M = LM[lvl]; long base = (long)n*ATOT + LBASE[lvl];
  __shared__ unsigned h[256];
  h[threadIdx.x] = 0;
  __syncthreads();
  unsigned prefix = ctl[C_PRE + t];
  int shift = 24 - 8*pass;
  for (int i = blockIdx.x*256 + threadIdx.x; i < M; i += gridDim.x*256) {
    unsigned key = fkey(scores[base + i]);
    if (pass == 0 || (key >> (shift+8)) == prefix)
      atomicAdd(&h[(key >> shift) & 255], 1u);
  }
  __syncthreads();
  if (h[threadIdx.x]) atomicAdd(&ctl[C_GH + t*256 + threadIdx.x], h[threadIdx.x]);
}

__global__ __launch_bounds__(256) void tk_pick(unsigned* ctl) {
  int t = blockIdx.x;
  if (threadIdx.x == 0) {
    unsigned kcur = ctl[C_KCUR + t];
    int digit = 0;
    for (int d = 255; d >= 0; --d) {
      unsigned c = ctl[C_GH + t*256 + d];
      if (kcur <= c) { digit = d; break; }
      kcur -= c;
    }
    ctl[C_KCUR + t] = kcur;
    ctl[C_PRE + t] = (ctl[C_PRE + t] << 8) | (unsigned)digit;
  }
  __syncthreads();
  ctl[C_GH + t*256 + threadIdx.x] = 0;
}

__global__ __launch_bounds__(256) void tk_compact(const float* __restrict__ scores,
    const float* __restrict__ comb, unsigned* ctl, float* cboxes, float* cscores) {
  int t = blockIdx.y; int lvl = t >> 1, n = t & 1;
  int M = LM[lvl]; long base = (long)n*ATOT + LBASE[lvl];
  unsigned thr = ctl[C_PRE + t];
  for (int i = blockIdx.x*256 + threadIdx.x; i < M; i += gridDim.x*256) {
    unsigned key = fkey(scores[base + i]);
    if (key > thr) {
      unsigned p = atomicAdd(&ctl[C_CNT + t], 1u);
      if (p < 6000u) decode_store(n, lvl, i, CBASE[lvl] + (int)p, comb, cboxes, cscores);
    } else if (key == thr) {
      unsigned p = atomicAdd(&ctl[C_TIE + t], 1u);
      if (p < 1024u) ctl[C_TIEIDX + t*1024 + p] = (unsigned)i;
    }
  }
}

__global__ void tk_finalize(const float* __restrict__ comb, unsigned* ctl,
                            float* cboxes, float* cscores) {
  int t = blockIdx.x; int lvl = t >> 1, n = t & 1;
  if (threadIdx.x != 0) return;
  int cnt = (int)ctl[C_CNT + t]; if (cnt > 6000) cnt = 6000;
  int need = 6000 - cnt;
  int tc = (int)ctl[C_TIE + t]; if (tc > 1024) tc = 1024;
  unsigned* tb = &ctl[C_TIEIDX + t*1024];
  for (int s = 0; s < need; ++s) {
    unsigned mn = 0xFFFFFFFFu; int mi = -1;
    for (int q = 0; q < tc; ++q) { if (tb[q] < mn) { mn = tb[q]; mi = q; } }
    int slot = CBASE[lvl] + cnt + s;
    if (mi >= 0) {
      tb[mi] = 0xFFFFFFFFu;
      decode_store(n, lvl, (int)mn, slot, comb, cboxes, cscores);
    } else {
      float* cbp = cboxes + ((long)n*MCAND + slot)*4;
      cbp[0]=cbp[1]=cbp[2]=cbp[3]=0.f;
      cscores[(long)n*MCAND + slot] = -3.0e38f;
    }
  }
}

__global__ void decode34(const float* __restrict__ comb, float* cboxes, float* cscores) {
  int n = blockIdx.y;
  int e = blockIdx.x*256 + threadIdx.x;
  if (e >= 3840) return;
  if (e < 3072) decode_store(n, 3, e, 18000 + e, comb, cboxes, cscores);
  else          decode_store(n, 4, e - 3072, 21072 + (e - 3072), comb, cboxes, cscores);
}

// =============== NMS: matrix pipeline ===============
__global__ __launch_bounds__(1024) void nms_select(
    const float* __restrict__ cscores, const float* __restrict__ cboxes,
    float* __restrict__ wt, unsigned* ctl) {
  const int n = blockIdx.x;
  if (ctl[N_DONE + n]) return;
  const int tid = threadIdx.x;
  const float* sc = cscores + (long)n*MCAND;
  const float* cb = cboxes + (long)n*MCAND*4;
  u64* skeyG   = ((u64*)(wt + NS_KEY)) + n*RCAP;
  float* boxO  = wt + NS_BOX + n*RCAP*4;
  float* areaG = wt + NS_AREA + n*RCAP;
  __shared__ u64 skey[RCAP];
  __shared__ unsigned hist[256];
  __shared__ unsigned sS[8];
  unsigned thrPrev = ctl[N_THRPREV + n];
  unsigned prefix = 0, kcur = RCAP;
  for (int pass = 0; pass < 4; ++pass) {
    if (tid < 256) hist[tid] = 0;
    __syncthreads();
    int shift = 24 - 8*pass;
    for (int i = tid; i < MCAND; i += 1024) {
      unsigned key = fkey(sc[i]);
      if (key < thrPrev && (pass == 0 || (key >> (shift+8)) == prefix))
        atomicAdd(&hist[(key >> shift) & 255], 1u);
    }
    __syncthreads();
    if (tid == 0) {
      if (pass == 0) { unsigned s = 0; for (int d = 0; d < 256; ++d) s += hist[d]; sS[2] = s; }
      if (sS[2] > RCAP) {
        unsigned kc = kcur; int digit = 0;
        for (int d = 255; d >= 0; --d) {
          unsigned c = hist[d];
          if (kc <= c) { digit = d; break; }
          kc -= c;
        }
        kcur = kc;
        prefix = (prefix << 8) | (unsigned)digit;
        sS[4] = prefix;
      } else sS[4] = 0;
    }
    __syncthreads();
    prefix = sS[4];
    if (sS[2] <= RCAP) break;
  }
  unsigned thr = (sS[2] <= RCAP) ? 0u : sS[4];
  if (tid == 0) sS[0] = 0;
  for (int i = tid; i < RCAP; i += 1024) skey[i] = 0;
  __syncthreads();
  for (int i = tid; i < MCAND; i += 1024) {
    unsigned key = fkey(sc[i]);
    if (key < thrPrev && key >= thr) {
      unsigned p = atomicAdd(&sS[0], 1u);
      if (p < RCAP) skey[p] = ((u64)key << 32) | (unsigned)(~i);
    }
  }
  __syncthreads();
  unsigned scnt = sS[0] > RCAP ? RCAP : sS[0];
  for (int kk = 2; kk <= RCAP; kk <<= 1) {
    for (int jj = kk >> 1; jj > 0; jj >>= 1) {
      for (int i = tid; i < RCAP; i += 1024) {
        int ixj = i ^ jj;
        if (ixj > i) {
          u64 a = skey[i], b = skey[ixj];
          bool up = ((i & kk) == 0);
          if ((a < b) == up) { skey[i] = b; skey[ixj] = a; }
        }
      }
      __syncthreads();
    }
  }
  for (int s = tid; s < RCAP; s += 1024) {
    u64 v = skey[s];
    skeyG[s] = v;
    float x1=0.f,y1=0.f,x2=0.f,y2=0.f,ar=0.f;
    if (v) {
      int idx = (int)(~(unsigned)v);
      float off = 2000.f * (float)lvl_of(idx);
      x1 = cb[idx*4+0] + off; y1 = cb[idx*4+1] + off;
      x2 = cb[idx*4+2] + off; y2 = cb[idx*4+3] + off;
      ar = (x2-x1)*(y2-y1);
    }
    boxO[s*4+0]=x1; boxO[s*4+1]=y1; boxO[s*4+2]=x2; boxO[s*4+3]=y2;
    areaG[s]=ar;
  }
  if (tid == 0) {
    ctl[N_SCNT + n] = scnt;
    ctl[N_THRPREV + n] = thr;
    if (thr == 0u) ctl[N_LAST + n] = 1;
    if (scnt == 0) ctl[N_DONE + n] = 1;
  }
}

__global__ __launch_bounds__(256) void nms_matrix(const float* __restrict__ wt_c,
                                                  float* __restrict__ wt, unsigned* ctl) {
  const int n = blockIdx.y;
  if (ctl[N_DONE + n]) return;
  const int bx = blockIdx.x;
  const int i0 = bx * 64;
  const int tid = threadIdx.x;
  const int wv = tid >> 6;
  const int lane = tid & 63;
  const float* boxO  = wt_c + NS_BOX + n*RCAP*4;
  const float* areaG = wt_c + NS_AREA + n*RCAP;
  const float* kbox  = wt_c + NS_KBOX + n*1024*5;
  u64* mask  = ((u64*)(wt + NS_MASK)) + (long)n*RCAP*64;
  u64* diagA = ((u64*)(wt + NS_DIAG)) + n*64*64;
  u64* psupW = ((u64*)(wt + NS_PSUP)) + n*64;
  int kt0 = (int)ctl[N_KEPT + n];
  __shared__ float rb[64][5];
  __shared__ unsigned psw[2];
  if (tid < 2) psw[tid] = 0;
  if (tid < 64) {
    rb[tid][0]=boxO[(i0+tid)*4+0]; rb[tid][1]=boxO[(i0+tid)*4+1];
    rb[tid][2]=boxO[(i0+tid)*4+2]; rb[tid][3]=boxO[(i0+tid)*4+3];
    rb[tid][4]=areaG[i0+tid];
  }
  __syncthreads();
  if (kt0 > 0) {
    for (int rr = 0; rr < 16; ++rr) {
      int il = wv*16 + rr;
      float rx1=rb[il][0], ry1=rb[il][1], rx2=rb[il][2], ry2=rb[il][3], rar=rb[il][4];
      bool s = false;
      for (int k = lane; k < kt0; k += 64) {
        float iou = iou_f(rx1,ry1,rx2,ry2,rar,
                          kbox[k*5+0],kbox[k*5+1],kbox[k*5+2],kbox[k*5+3],kbox[k*5+4]);
        s |= (iou > 0.7f);
      }
      u64 bal = __ballot(s);
      if (lane == 0 && bal) atomicOr(&psw[il>>5], 1u << (il & 31));
    }
  }
  __syncthreads();
  if (tid == 0) psupW[bx] = ((u64)psw[1] << 32) | psw[0];
  for (int w = 0; w < 64; ++w) {
    int cidx = w*64 + lane;
    float cx1=boxO[cidx*4+0], cy1=boxO[cidx*4+1], cx2=boxO[cidx*4+2], cy2=boxO[cidx*4+3];
    float car=areaG[cidx];
    #pragma unroll 4
    for (int rr = 0; rr < 16; ++rr) {
      int il = wv*16 + rr;
      int i = i0 + il;
      float iou = iou_f(rb[il][0],rb[il][1],rb[il][2],rb[il][3],rb[il][4],
                        cx1,cy1,cx2,cy2,car);
      bool bit = (iou > 0.7f) && (cidx > i);
      u64 m = __ballot(bit);
      if (lane == 0) {
        mask[(long)i*64 + w] = m;
        if (w == bx) diagA[bx*64 + il] = m;
      }
    }
  }
}

__global__ __launch_bounds__(64) void nms_scan(
    const float* __restrict__ cscores, const float* __restrict__ cboxes,
    float* __restrict__ wt, unsigned* ctl, float* __restrict__ dout) {
  const int n = blockIdx.x;
  if (ctl[N_DONE + n]) return;
  const int lane = threadIdx.x;
  const float* cb = cboxes + (long)n*MCAND*4;
  u64* skeyG = ((u64*)(wt + NS_KEY)) + n*RCAP;
  const float* boxO  = wt + NS_BOX + n*RCAP*4;
  const float* areaG = wt + NS_AREA + n*RCAP;
  u64* mask  = ((u64*)(wt + NS_MASK)) + (long)n*RCAP*64;
  u64* diagA = ((u64*)(wt + NS_DIAG)) + n*64*64;
  u64* psupW = ((u64*)(wt + NS_PSUP)) + n*64;
  float* kbox = wt + NS_KBOX + n*1024*5;
  float* keepB = dout + KB_OFF + (long)n*4*POSTK;
  float* keepS = dout + KS_OFF + (long)n*POSTK;
  float* keepV = dout + KV_OFF + (long)n*POSTK;
  int scnt = (int)ctl[N_SCNT + n];
  int kt = (int)ctl[N_KEPT + n];
  __shared__ u64 alive[64];
  {
    int rem = scnt - lane*64;
    u64 a = rem >= 64 ? ~0ull : (rem > 0 ? ((1ull << rem) - 1ull) : 0ull);
    alive[lane] = a & ~psupW[lane];
  }
  __syncthreads();
  for (int c = 0; c < 64 && kt < POSTK; ++c) {
    u64 w64 = alive[c];
    if (!w64) continue;
    u64 diag = diagA[c*64 + lane];
    u64 kb = 0;
    while (w64) {
      int b = __ffsll(w64) - 1;
      kb |= (1ull << b);
      w64 &= ~(1ull << b);
      u64 sup = __shfl(diag, b);
      w64 &= ~sup;
      if (++kt >= POSTK) break;
    }
    alive[c] = 0;
    if ((kb >> lane) & 1) {
      int base = kt - (int)__popcll(kb);
      int pos = base + (int)__popcll(kb & ((1ull << lane) - 1ull));
      int s = c*64 + lane;
      u64 v = skeyG[s];
      int idx = (int)(~(unsigned)v);
      keepB[pos*4+0]=cb[idx*4+0]; keepB[pos*4+1]=cb[idx*4+1];
      keepB[pos*4+2]=cb[idx*4+2]; keepB[pos*4+3]=cb[idx*4+3];
      keepS[pos] = unfkey((unsigned)(v >> 32));
      keepV[pos] = 1.f;
      kbox[pos*5+0]=boxO[s*4+0]; kbox[pos*5+1]=boxO[s*4+1];
      kbox[pos*5+2]=boxO[s*4+2]; kbox[pos*5+3]=boxO[s*4+3];
      kbox[pos*5+4]=areaG[s];
    }
    __syncthreads();
    if (kb && lane > c && alive[lane]) {
      u64 acc = 0, m = kb;
      while (m) {
        int b = __ffsll(m) - 1; m &= m - 1;
        acc |= mask[(long)(c*64 + b)*64 + lane];
      }
      if (acc) alive[lane] &= ~acc;
    }
    __syncthreads();
  }
  if (lane == 0) {
    ctl[N_KEPT + n] = (unsigned)kt;
    if (kt >= POSTK || ctl[N_LAST + n]) ctl[N_DONE + n] = 1;
  }
}

__device__ inline u64 shfl_down_u64d(u64 v, int o) {
  unsigned hi = __shfl_down((unsigned)(v >> 32), o);
  unsigned lo = __shfl_down((unsigned)v, o);
  return ((u64)hi << 32) | lo;
}
__global__ __launch_bounds__(1024) void nms_fill(
    const float* __restrict__ cscores, const float* __restrict__ cboxes,
    unsigned* ctl, float* __restrict__ dout) {
  const int n = blockIdx.x;
  const int tid = threadIdx.x;
  const int lane = tid & 63;
  const int wid = tid >> 6;
  const float* sc = cscores + (long)n*MCAND;
  const float* cb = cboxes + (long)n*MCAND*4;
  float* keepB = dout + KB_OFF + (long)n*4*POSTK;
  float* keepS = dout + KS_OFF + (long)n*POSTK;
  float* keepV = dout + KV_OFF + (long)n*POSTK;
  __shared__ u64 wred[16];
  __shared__ u64 sBest;
  u64 best = 0;
  for (int i = tid; i < 6000; i += 1024) {
    u64 v = ((u64)fkey(sc[i]) << 32) | (unsigned)(~i);
    if (v > best) best = v;
  }
  for (int o = 32; o > 0; o >>= 1) {
    u64 ov = shfl_down_u64d(best, o);
    if (ov > best) best = ov;
  }
  if (lane == 0) wred[wid] = best;
  __syncthreads();
  if (tid == 0) {
    u64 b = 0;
    for (int i = 0; i < 16; ++i) if (wred[i] > b) b = wred[i];
    sBest = b;
  }
  __syncthreads();
  int kt = (int)ctl[N_KEPT + n];
  int bidx = (int)(~(unsigned)sBest);
  float b0 = cb[bidx*4+0], b1 = cb[bidx*4+1], b2 = cb[bidx*4+2], b3 = cb[bidx*4+3];
  float bsc = sc[bidx];
  for (int s2 = kt + tid; s2 < POSTK; s2 += 1024) {
    keepB[s2*4+0]=b0; keepB[s2*4+1]=b1; keepB[s2*4+2]=b2; keepB[s2*4+3]=b3;
    keepS[s2] = bsc; keepV[s2] = 0.f;
  }
}

// ---------------- launcher ----------------
extern "C" void kernel_launch(void* const* d_in, const int* in_sizes, int n_in,
                              void* d_out, int out_size, void* d_ws, size_t ws_size,
                              hipStream_t stream) {
  const float* feats[5];
  for (int i = 0; i < 5; ++i) feats[i] = (const float*)d_in[i];
  const float* conv_w  = (const float*)d_in[5];
  const float* conv_b  = (const float*)d_in[6];
  const float* obj_w   = (const float*)d_in[7];
  const float* obj_b   = (const float*)d_in[8];
  const float* delta_w = (const float*)d_in[9];
  const float* delta_b = (const float*)d_in[10];
  float* out = (float*)d_out;
  float* ws = (float*)d_ws;

  const bool big = ws_size >= (size_t)FT_END * 4ull;
  float *t, *scores, *cboxes, *cscores, *wp;
  unsigned* ctl;
  if (big) {
    t = ws + FT_T; scores = ws + FT_SC; cboxes = ws + FT_CB;
    cscores = ws + FT_CS; ctl = (unsigned*)(ws + FT_CTL); wp = ws + FT_WP;
  } else {
    t = ws + WS_T; scores = ws + WS_SC; cboxes = ws + WS_CB;
    cscores = ws + WS_CS; ctl = (unsigned*)(ws + WS_CTL); wp = ws + WS_WP;
  }

  static const int LWh[5]    = {256,128,64,32,16};
  static const int LBASEh[5] = {0,196608,245760,258048,261120};

  wprep_mfma<<<dim3(2304), dim3(256), 0, stream>>>(conv_w, (f16*)wp);
  init_ctl<<<dim3(1), dim3(256), 0, stream>>>(ctl);

  if (big) {
    conv_big<<<dim3(682), dim3(1024), 0, stream>>>(
        feats[0], feats[1], feats[2], feats[3], feats[4], (const f16*)wp, conv_b,
        obj_w, obj_b, delta_w, delta_b, out, scores);
  } else {
    for (int n = 0; n < 2; ++n) {
      for (int lvl = 0; lvl < 5; ++lvl) {
        int H = LWh[lvl], W = LWh[lvl], HW = H*W;
        conv_lvl_mfma<<<dim3(W/16, H/8), dim3(256), 0, stream>>>(
            feats[lvl] + (long)n*256*HW, (const f16*)wp, conv_b, t, H, W);
        int hb = (HW + 1023) / 1024;
        heads1x1<<<dim3(hb), dim3(256), 0, stream>>>(
            t, obj_w, obj_b, delta_w, delta_b, out, scores, HW, LBASEh[lvl], n);
      }
    }
  }

  for (int p = 0; p < 4; ++p) {
    tk_hist<<<dim3(48,6), dim3(256), 0, stream>>>(scores, ctl, p);
    tk_pick<<<dim3(6), dim3(256), 0, stream>>>(ctl);
  }
  tk_compact<<<dim3(48,6), dim3(256), 0, stream>>>(scores, out, ctl, cboxes, cscores);
  tk_finalize<<<dim3(6), dim3(64), 0, stream>>>(out, ctl, cboxes, cscores);
  decode34<<<dim3(15,2), dim3(256), 0, stream>>>(out, cboxes, cscores);
  for (int b = 0; b < 6; ++b) {
    nms_select<<<dim3(2), dim3(1024), 0, stream>>>(cscores, cboxes, t, ctl);
    nms_matrix<<<dim3(64,2), dim3(256), 0, stream>>>(t, t, ctl);
    nms_scan<<<dim3(2), dim3(64), 0, stream>>>(cscores, cboxes, t, ctl, out);
  }
  nms_fill<<<dim3(2), dim3(1024), 0, stream>>>(cscores, cboxes, ctl, out);
}

// Round 6
// 1640.371 us; speedup vs baseline: 3.2360x; 3.2360x over previous
//
#include <hip/hip_runtime.h>
#include <math.h>

// ---------------- problem constants ----------------
#define ATOT 261888          // sum over levels of H*W*3
#define MCAND 21840          // 6000+6000+6000+3072+768 candidates per image
#define POSTK 1000
#define CMB (2*ATOT*5)       // combined output floats = 2618880
#define KB_OFF CMB           // keep_boxes offset in d_out
#define KS_OFF (CMB+8000)    // keep_scores
#define KV_OFF (CMB+10000)   // valid
#define SCALE_CLAMP 4.135166556742356f
#define RCAP 4096

typedef unsigned long long u64;

// ---------------- fallback (small-ws) layout, float units ----------------
#define WS_T   0
#define WS_SC  (256*65536)
#define WS_CB  (WS_SC + 2*ATOT)
#define WS_CS  (WS_CB + 2*MCAND*4)
#define WS_CTL (WS_CS + 2*MCAND)

// ctl indices (u32)
#define C_PRE 0
#define C_KCUR 6
#define C_CNT 12
#define C_TIE 18
#define N_THRPREV 24
#define N_KEPT 26
#define N_DONE 28
#define N_SCNT 30
#define N_LAST 32
#define C_GH 40
#define C_TIEIDX (C_GH + 6*256)
#define CTL_SIZE (C_TIEIDX + 6*1024)
#define WS_WP  (WS_CTL + CTL_SIZE)

// ---------------- fused (big-ws) layout, float units ----------------
#define FT_T   0
#define FT_TSZ 22347776                 // 256 * 87296 (all levels, one image)
#define FT_SC  22347776
#define FT_CB  (FT_SC + 2*ATOT)         // 22871552
#define FT_CS  (FT_CB + 2*MCAND*4)      // 23046272
#define FT_CTL (FT_CS + 2*MCAND)        // 23089952
#define FT_WP  (FT_CTL + CTL_SIZE)      // 23097672
#define FT_END (FT_WP + 589824)         // 23687496 floats = 94,749,984 B

// ---- NMS scratch inside the (dead-by-then) t buffer ----
#define NS_KEY  0
#define NS_BOX  16384
#define NS_AREA 49152
#define NS_DIAG 57344
#define NS_PSUP 73728
#define NS_KBOX 73984
#define NS_MASK 84224                   // end 1,132,800 floats

__device__ const int LW[5]    = {256,128,64,32,16};
__device__ const int LM[5]    = {196608,49152,12288,3072,768};
__device__ const int LBASE[5] = {0,196608,245760,258048,261120};
__device__ const int LSTR[5]  = {4,8,16,32,64};
__device__ const int LSZ[5]   = {32,64,128,256,512};
__device__ const int CBASE[5] = {0,6000,12000,18000,21072};
__device__ const int TOFF[5]  = {0,16777216,20971520,22020096,22282240}; // 256*cumHW

__device__ inline unsigned fkey(float f) {
  unsigned u = __float_as_uint(f);
  return u ^ (unsigned)(((int)u >> 31) | 0x80000000);
}
__device__ inline float unfkey(unsigned k) {
  unsigned u = (k & 0x80000000u) ? (k ^ 0x80000000u) : ~k;
  return __uint_as_float(u);
}
__device__ inline int lvl_of(int idx) {
  return idx < 6000 ? 0 : idx < 12000 ? 1 : idx < 18000 ? 2 : idx < 21072 ? 3 : 4;
}
__device__ inline float iou_f(float ax1,float ay1,float ax2,float ay2,float aar,
                              float bx1,float by1,float bx2,float by2,float bar) {
  float ix1 = fmaxf(ax1,bx1), iy1 = fmaxf(ay1,by1);
  float ix2 = fminf(ax2,bx2), iy2 = fminf(ay2,by2);
  float inter = fmaxf(ix2-ix1,0.f) * fmaxf(iy2-iy1,0.f);
  return inter / (aar + bar - inter + 1e-9f);
}

// =========================================================================
// MFMA conv: f16 hi/lo split (inputs & weights pre-scaled by 2^11; epilogue
// rescales by 2^-22). 3 MFMAs (hh, lh, hl) per nominal fp32 product.
// Big path (round-4 structure, verified 679us): 682 blocks x 512 threads
// (8 waves, 2/SIMD, 256 unified regs/wave — DO NOT raise block size: 1024thr
// forces 128 regs/wave and spills acc to scratch, round-5 fiasco).
// Round-6 change: conflict-free [ks][p][8] LDS layout (b128 read AND write
// at consecutive 16B/lane) replacing the 80B-stride f16x2 layout (8-way
// write conflicts, SQ_LDS_BANK_CONFLICT 3e7).
// =========================================================================
typedef _Float16 f16;
typedef _Float16 f16x2 __attribute__((ext_vector_type(2)));
typedef _Float16 f16x8 __attribute__((ext_vector_type(8)));
typedef float f32x4 __attribute__((ext_vector_type(4)));

#define MFMA16(a,b,c) __builtin_amdgcn_mfma_f32_16x16x32_f16(a,b,c,0,0,0)
#define AST 40            // fallback-path padded channel stride (f16)
#define WHALF 589824      // f16 elements per half (hi block / lo block)

// weight prep: conv_w[oc][ci][kh][kw] fp32 ->
//   wsp[h][t][kc][ks][oc][j] f16, h in {hi,lo}, ci = kc*32+ks*8+j, t = kh*3+kw
__global__ __launch_bounds__(256) void wprep_mfma(const float* __restrict__ wgt,
                                                  f16* __restrict__ wsp) {
  int o = blockIdx.x*256 + threadIdx.x;
  if (o >= WHALF) return;
  int j  = o & 7;
  int oc = (o >> 3) & 255;
  int ks = (o >> 11) & 3;
  int kc = (o >> 13) & 7;
  int t  = o >> 16;
  int ci = kc*32 + ks*8 + j;
  float v = wgt[(oc*256 + ci)*9 + t] * 2048.f;
  f16 hi = (f16)v;
  f16 lo = (f16)(v - (float)hi);
  wsp[o] = hi;
  wsp[WHALF + o] = lo;
}

// ---------------- BIG-TILE fused conv+heads (both images, one dispatch) ----
// block: 16x16 px, 8 waves (rg 0/1 rows, cg 0..3 oc-slices of 64).
// LDS layout: A[(ks*324 + p)*8 + j], ci = ks*8 + j within 32-chan chunk.
// 1296 units (4 ks x 324 halo px) per buffer; unit write = one b128.
#define ABUF2 10368       // f16 per Ah (or Al) block = 1296*8
#define SBUF2 20736       // f16 per full buffer (Ah+Al)

__global__ __launch_bounds__(512,2) void conv_big(
    const float* __restrict__ f0, const float* __restrict__ f1,
    const float* __restrict__ f2, const float* __restrict__ f3,
    const float* __restrict__ f4, const f16* __restrict__ wsp,
    const float* __restrict__ bias,
    const float* __restrict__ ow, const float* __restrict__ obp,
    const float* __restrict__ dwp, const float* __restrict__ dbp,
    float* __restrict__ comb, float* __restrict__ scores) {
  __shared__ __align__(16) char SBc[82944];    // 2 buffers x 41472 B
  __shared__ float wHs[15][256];
  const int tid = threadIdx.x;

  // block geometry: id -> (image, level, tile). 341 blocks per image.
  int id = blockIdx.x;
  int n = (id >= 341) ? 1 : 0;
  int rem = id - n*341;
  int lvl, tile;
  if (rem < 256)      { lvl = 0; tile = rem; }
  else if (rem < 320) { lvl = 1; tile = rem - 256; }
  else if (rem < 336) { lvl = 2; tile = rem - 320; }
  else if (rem < 340) { lvl = 3; tile = rem - 336; }
  else                { lvl = 4; tile = 0; }
  const int W = LW[lvl], H = W, HW = W*W;
  const int tw = W >> 4;
  const int ty0 = tile / tw, tx0 = tile - ty0*tw;
  const int x0 = tx0*16, y0 = ty0*16;
  const int lbase = LBASE[lvl];
  const float* in = (lvl==0?f0:lvl==1?f1:lvl==2?f2:lvl==3?f3:f4) + (long)n*256*HW;

  const int wv   = tid >> 6;
  const int lane = tid & 63;
  const int l15  = lane & 15;
  const int ks   = lane >> 4;
  const int rg   = wv >> 2;      // row group: rows rg*8 .. rg*8+7
  const int cg   = wv & 3;       // oc slice:  oc cg*64 .. cg*64+63

  // stage head weights once (read in epilogue, after barriers)
  for (int i = tid; i < 768; i += 512)  wHs[i>>8][i&255] = ow[i];
  for (int i = tid; i < 3072; i += 512) wHs[3+(i>>8)][i&255] = dwp[i];

  // ---- per-thread staging geometry (loop-invariant over kc) ----
  // unit u = ksu*324 + pu; units per thread: tid, tid+512, tid+1024 (<1296).
  int ubo0, ubo1, ubo2; bool uin0, uin1, uin2;
  {
    int u = tid;
    int ksu = u / 324, pu = u - ksu*324;
    int hy = pu/18, hx = pu - hy*18;
    int gy = y0 + hy - 1, gx = x0 + hx - 1;
    uin0 = (gy>=0) & (gy<H) & (gx>=0) & (gx<W);
    ubo0 = ksu*8*HW + min(max(gy,0),H-1)*W + min(max(gx,0),W-1);
  }
  {
    int u = tid + 512;
    int ksu = u / 324, pu = u - ksu*324;
    int hy = pu/18, hx = pu - hy*18;
    int gy = y0 + hy - 1, gx = x0 + hx - 1;
    uin1 = (gy>=0) & (gy<H) & (gx>=0) & (gx<W);
    ubo1 = ksu*8*HW + min(max(gy,0),H-1)*W + min(max(gx,0),W-1);
  }
  const bool has2 = tid < 272;
  {
    int u = has2 ? tid + 1024 : 0;
    int ksu = u / 324, pu = u - ksu*324;
    int hy = pu/18, hx = pu - hy*18;
    int gy = y0 + hy - 1, gx = x0 + hx - 1;
    uin2 = (gy>=0) & (gy<H) & (gx>=0) & (gx<W);
    ubo2 = ksu*8*HW + min(max(gy,0),H-1)*W + min(max(gx,0),W-1);
  }

  float sv0[8], sv1[8], sv2[8];
  // load + convert + write (round-4 scheduling: all inline, double-buffered)
  auto stage = [&](int kc, int b) {
    const float* q = in + (size_t)(kc*32)*HW;
    #pragma unroll
    for (int j = 0; j < 8; ++j) sv0[j] = q[ubo0 + j*HW];
    #pragma unroll
    for (int j = 0; j < 8; ++j) sv1[j] = q[ubo1 + j*HW];
    if (has2) {
      #pragma unroll
      for (int j = 0; j < 8; ++j) sv2[j] = q[ubo2 + j*HW];
    }
    f16* AhB = (f16*)SBc + b*SBUF2;
    f16* AlB = AhB + ABUF2;
    f16x8 vh, vl;
    #pragma unroll
    for (int j = 0; j < 8; ++j) {
      float v = uin0 ? sv0[j]*2048.f : 0.f;
      f16 h = (f16)v; vh[j] = h; vl[j] = (f16)(v - (float)h);
    }
    *(f16x8*)&AhB[tid*8] = vh;
    *(f16x8*)&AlB[tid*8] = vl;
    #pragma unroll
    for (int j = 0; j < 8; ++j) {
      float v = uin1 ? sv1[j]*2048.f : 0.f;
      f16 h = (f16)v; vh[j] = h; vl[j] = (f16)(v - (float)h);
    }
    *(f16x8*)&AhB[(tid+512)*8] = vh;
    *(f16x8*)&AlB[(tid+512)*8] = vl;
    if (has2) {
      #pragma unroll
      for (int j = 0; j < 8; ++j) {
        float v = uin2 ? sv2[j]*2048.f : 0.f;
        f16 h = (f16)v; vh[j] = h; vl[j] = (f16)(v - (float)h);
      }
      *(f16x8*)&AhB[(tid+1024)*8] = vh;
      *(f16x8*)&AlB[(tid+1024)*8] = vl;
    }
  };

  const f32x4 vzero = {0.f, 0.f, 0.f, 0.f};
  f32x4 acc[8][4];
  #pragma unroll
  for (int mt = 0; mt < 8; ++mt)
    #pragma unroll
    for (int nt = 0; nt < 4; ++nt) acc[mt][nt] = vzero;

  stage(0, 0);
  __syncthreads();

  for (int kc = 0; kc < 8; ++kc) {
    const int b = kc & 1;
    if (kc < 7) stage(kc + 1, b ^ 1);    // writes other buffer: no conflict
    const f16* AhB = (const f16*)SBc + b*SBUF2;
    const f16* AlB = AhB + ABUF2;
    for (int t = 0; t < 9; ++t) {
      const int tyk = t / 3, txk = t - (t/3)*3;
      const f16* wb = wsp + (((t*8 + kc)*4 + ks)*256 + cg*64 + l15)*8;
      f16x8 Bh0 = *(const f16x8*)(wb);
      f16x8 Bh1 = *(const f16x8*)(wb + 128);
      f16x8 Bh2 = *(const f16x8*)(wb + 256);
      f16x8 Bh3 = *(const f16x8*)(wb + 384);
      f16x8 Bl0 = *(const f16x8*)(wb + WHALF);
      f16x8 Bl1 = *(const f16x8*)(wb + WHALF + 128);
      f16x8 Bl2 = *(const f16x8*)(wb + WHALF + 256);
      f16x8 Bl3 = *(const f16x8*)(wb + WHALF + 384);
      #pragma unroll
      for (int mt = 0; mt < 8; ++mt) {
        const int p = (rg*8 + mt + tyk)*18 + l15 + txk;
        f16x8 Af = *(const f16x8*)&AhB[(ks*324 + p)*8];
        f16x8 Ae = *(const f16x8*)&AlB[(ks*324 + p)*8];
        acc[mt][0] = MFMA16(Af, Bh0, acc[mt][0]);
        acc[mt][1] = MFMA16(Af, Bh1, acc[mt][1]);
        acc[mt][2] = MFMA16(Af, Bh2, acc[mt][2]);
        acc[mt][3] = MFMA16(Af, Bh3, acc[mt][3]);
        acc[mt][0] = MFMA16(Ae, Bh0, acc[mt][0]);
        acc[mt][1] = MFMA16(Ae, Bh1, acc[mt][1]);
        acc[mt][2] = MFMA16(Ae, Bh2, acc[mt][2]);
        acc[mt][3] = MFMA16(Ae, Bh3, acc[mt][3]);
        acc[mt][0] = MFMA16(Af, Bl0, acc[mt][0]);
        acc[mt][1] = MFMA16(Af, Bl1, acc[mt][1]);
        acc[mt][2] = MFMA16(Af, Bl2, acc[mt][2]);
        acc[mt][3] = MFMA16(Af, Bl3, acc[mt][3]);
      }
    }
    __syncthreads();                     // buffer b free; b^1 staged complete
  }

  // ---- fused heads epilogue (no t-buffer) ----
  const float rs = 1.f / 4194304.f;      // 2^-22, exact
  float* part = (float*)SBc;             // staging dead; reuse (30,720 B)
  float bb[4];
  #pragma unroll
  for (int nt = 0; nt < 4; ++nt) bb[nt] = bias[cg*64 + nt*16 + l15];

  #pragma unroll
  for (int mt = 0; mt < 8; ++mt) {
    f32x4 y[4];
    #pragma unroll
    for (int nt = 0; nt < 4; ++nt) {
      f32x4 a = acc[mt][nt];
      y[nt][0] = fmaxf(a[0]*rs + bb[nt], 0.f);
      y[nt][1] = fmaxf(a[1]*rs + bb[nt], 0.f);
      y[nt][2] = fmaxf(a[2]*rs + bb[nt], 0.f);
      y[nt][3] = fmaxf(a[3]*rs + bb[nt], 0.f);
    }
    #pragma unroll
    for (int j = 0; j < 15; ++j) {
      float w0 = wHs[j][cg*64 + l15];
      float w1 = wHs[j][cg*64 + 16 + l15];
      float w2 = wHs[j][cg*64 + 32 + l15];
      float w3 = wHs[j][cg*64 + 48 + l15];
      f32x4 p4;
      p4[0] = y[0][0]*w0 + y[1][0]*w1 + y[2][0]*w2 + y[3][0]*w3;
      p4[1] = y[0][1]*w0 + y[1][1]*w1 + y[2][1]*w2 + y[3][1]*w3;
      p4[2] = y[0][2]*w0 + y[1][2]*w1 + y[2][2]*w2 + y[3][2]*w3;
      p4[3] = y[0][3]*w0 + y[1][3]*w1 + y[2][3]*w2 + y[3][3]*w3;
      #pragma unroll
      for (int m = 1; m < 16; m <<= 1) {   // reduce the 16 oc-lanes
        p4[0] += __shfl_xor(p4[0], m);
        p4[1] += __shfl_xor(p4[1], m);
        p4[2] += __shfl_xor(p4[2], m);
        p4[3] += __shfl_xor(p4[3], m);
      }
      if (l15 == 0) {
        float* pp = part + ((((cg*2 + rg)*8 + mt)*4 + ks)*15 + j)*4;
        pp[0] = p4[0]; pp[1] = p4[1]; pp[2] = p4[2]; pp[3] = p4[3];
      }
    }
  }
  __syncthreads();
  if (tid < 256) {
    int rg2 = tid >> 7, mt = (tid >> 4) & 7, xi = tid & 15;
    int k2 = xi >> 2, xj = xi & 3;
    float v[15];
    #pragma unroll
    for (int j = 0; j < 15; ++j) {
      float s = 0.f;
      #pragma unroll
      for (int c2 = 0; c2 < 4; ++c2)
        s += part[((((c2*2 + rg2)*8 + mt)*4 + k2)*15 + j)*4 + xj];
      v[j] = s;
    }
    int pos = (y0 + rg2*8 + mt)*W + x0 + xi;
    long base = (long)n*ATOT + lbase + (long)pos*3;
    #pragma unroll
    for (int a = 0; a < 3; ++a) {
      float lg = v[a] + obp[a];
      comb[(base+a)*5] = lg;
      scores[(long)n*ATOT + lbase + pos*3 + a] = lg;
      #pragma unroll
      for (int q = 0; q < 4; ++q)
        comb[(base+a)*5 + 1 + q] = v[3 + a*4 + q] + dbp[a*4+q];
    }
  }
}

// ---------------- fallback conv (small-ws): 16x8 tile, writes t ----------
__global__ __launch_bounds__(256,2) void conv_lvl_mfma(
    const float* __restrict__ in, const f16* __restrict__ wsp,
    const float* __restrict__ bias, float* __restrict__ outp, int H, int W) {
  __shared__ __align__(16) char SBc[28800];
  f16* Ah = (f16*)SBc;
  f16* Al = (f16*)(SBc + 14400);
  const int tid  = threadIdx.x;
  const int wv   = tid >> 6;
  const int lane = tid & 63;
  const int l15  = lane & 15;
  const int ks   = lane >> 4;
  const int HW   = H * W;
  const int x0 = blockIdx.x*16, y0 = blockIdx.y*8;

  const f32x4 vzero = {0.f, 0.f, 0.f, 0.f};
  f32x4 acc[8][4];
  #pragma unroll
  for (int mt = 0; mt < 8; ++mt)
    #pragma unroll
    for (int nt = 0; nt < 4; ++nt) acc[mt][nt] = vzero;

  for (int kc = 0; kc < 8; ++kc) {
    __syncthreads();
    for (int i = tid; i < 2880; i += 256) {
      int cp = i / 180; int p = i - cp*180;
      int hy = p / 18, hx = p - hy*18;
      int gy = y0 + hy - 1, gx = x0 + hx - 1;
      float v0 = 0.f, v1 = 0.f;
      if (gy >= 0 && gy < H && gx >= 0 && gx < W) {
        const float* q = in + (long)(kc*32 + 2*cp)*HW + gy*W + gx;
        v0 = q[0] * 2048.f;
        v1 = q[HW] * 2048.f;
      }
      f16 h0 = (f16)v0, h1 = (f16)v1;
      f16 e0 = (f16)(v0 - (float)h0), e1 = (f16)(v1 - (float)h1);
      f16x2 ph; ph[0] = h0; ph[1] = h1;
      f16x2 pl; pl[0] = e0; pl[1] = e1;
      *(f16x2*)&Ah[p*AST + 2*cp] = ph;
      *(f16x2*)&Al[p*AST + 2*cp] = pl;
    }
    __syncthreads();
    for (int t = 0; t < 9; ++t) {
      const int tyk = t / 3, txk = t - (t/3)*3;
      const f16* wb = wsp + (((t*8 + kc)*4 + ks)*256 + wv*64 + l15)*8;
      f16x8 Bh0 = *(const f16x8*)(wb);
      f16x8 Bh1 = *(const f16x8*)(wb + 128);
      f16x8 Bh2 = *(const f16x8*)(wb + 256);
      f16x8 Bh3 = *(const f16x8*)(wb + 384);
      f16x8 Bl0 = *(const f16x8*)(wb + WHALF);
      f16x8 Bl1 = *(const f16x8*)(wb + WHALF + 128);
      f16x8 Bl2 = *(const f16x8*)(wb + WHALF + 256);
      f16x8 Bl3 = *(const f16x8*)(wb + WHALF + 384);
      #pragma unroll
      for (int mt = 0; mt < 8; ++mt) {
        const int p = (mt + tyk)*18 + l15 + txk;
        f16x8 Af = *(const f16x8*)&Ah[p*AST + ks*8];
        f16x8 Ae = *(const f16x8*)&Al[p*AST + ks*8];
        acc[mt][0] = MFMA16(Af, Bh0, acc[mt][0]);
        acc[mt][1] = MFMA16(Af, Bh1, acc[mt][1]);
        acc[mt][2] = MFMA16(Af, Bh2, acc[mt][2]);
        acc[mt][3] = MFMA16(Af, Bh3, acc[mt][3]);
        acc[mt][0] = MFMA16(Ae, Bh0, acc[mt][0]);
        acc[mt][1] = MFMA16(Ae, Bh1, acc[mt][1]);
        acc[mt][2] = MFMA16(Ae, Bh2, acc[mt][2]);
        acc[mt][3] = MFMA16(Ae, Bh3, acc[mt][3]);
        acc[mt][0] = MFMA16(Af, Bl0, acc[mt][0]);
        acc[mt][1] = MFMA16(Af, Bl1, acc[mt][1]);
        acc[mt][2] = MFMA16(Af, Bl2, acc[mt][2]);
        acc[mt][3] = MFMA16(Af, Bl3, acc[mt][3]);
      }
    }
  }
  const float rs = 1.f / 4194304.f;
  #pragma unroll
  for (int nt = 0; nt < 4; ++nt) {
    int oc = wv*64 + nt*16 + l15;
    float bbv = bias[oc];
    #pragma unroll
    for (int mt = 0; mt < 8; ++mt) {
      f32x4 a = acc[mt][nt];
      float4 v;
      v.x = fmaxf(a[0]*rs + bbv, 0.f);
      v.y = fmaxf(a[1]*rs + bbv, 0.f);
      v.z = fmaxf(a[2]*rs + bbv, 0.f);
      v.w = fmaxf(a[3]*rs + bbv, 0.f);
      *(float4*)&outp[(long)oc*HW + (y0+mt)*W + x0 + ks*4] = v;
    }
  }
}

// ---------------- 1x1 heads (fallback path only) ----------------
__global__ __launch_bounds__(256) void heads1x1(
    const float* __restrict__ t, const float* __restrict__ ow, const float* __restrict__ ob,
    const float* __restrict__ dw, const float* __restrict__ db,
    float* __restrict__ comb, float* __restrict__ scores, int HW, int lbase, int n) {
  __shared__ float wS[15][256];
  const int tid = threadIdx.x;
  for (int i = tid; i < 3*256; i += 256) wS[i>>8][i&255] = ow[i];
  for (int i = tid; i < 12*256; i += 256) wS[3+(i>>8)][i&255] = dw[i];
  __syncthreads();
  int p0 = (blockIdx.x*256 + threadIdx.x)*4;
  if (p0 >= HW) return;
  float acc[15][4] = {};
  for (int c = 0; c < 256; ++c) {
    float4 v = *(const float4*)&t[c*HW + p0];
    float vv[4] = {v.x, v.y, v.z, v.w};
    #pragma unroll
    for (int k = 0; k < 15; ++k) {
      float w = wS[k][c];
      #pragma unroll
      for (int j = 0; j < 4; ++j) acc[k][j] += w * vv[j];
    }
  }
  float obv[3]; for (int i2 = 0; i2 < 3; ++i2) obv[i2] = ob[i2];
  float dbv[12]; for (int i2 = 0; i2 < 12; ++i2) dbv[i2] = db[i2];
  for (int j = 0; j < 4; ++j) {
    int pos = p0 + j;
    long base = (long)n*ATOT + lbase + (long)pos*3;
    #pragma unroll
    for (int a = 0; a < 3; ++a) {
      float lg = acc[a][j] + obv[a];
      comb[(base+a)*5] = lg;
      scores[(long)n*ATOT + lbase + pos*3 + a] = lg;
      #pragma unroll
      for (int q = 0; q < 4; ++q)
        comb[(base+a)*5 + 1 + q] = acc[3 + a*4 + q][j] + dbv[a*4+q];
    }
  }
}

// ---------------- decode ----------------
__device__ void decode_store(int n, int lvl, int idx, int slot,
                             const float* comb, float* cboxes, float* cscores) {
  int W = LW[lvl];
  int a = idx % 3; int p = idx / 3;
  int wx = p % W, hy = p / W;
  double r = (a == 0) ? 0.5 : (a == 1) ? 1.0 : 2.0;
  double sz = (double)LSZ[lvl];
  double wsd = sqrt(sz*sz/r);
  double hsd = wsd * r;
  double cxd = (double)(wx * LSTR[lvl]);
  double cyd = (double)(hy * LSTR[lvl]);
  float ax1 = (float)(cxd - 0.5*wsd), ay1 = (float)(cyd - 0.5*hsd);
  float ax2 = (float)(cxd + 0.5*wsd), ay2 = (float)(cyd + 0.5*hsd);
  float aw = ax2 - ax1, ah = ay2 - ay1;
  float acx = ax1 + 0.5f*aw, acy = ay1 + 0.5f*ah;
  long g = (long)n*ATOT + LBASE[lvl] + idx;
  const float* cm = comb + g*5;
  float sc = cm[0];
  float dx = cm[1], dy = cm[2], dwv = cm[3], dhv = cm[4];
  dwv = fminf(dwv, SCALE_CLAMP); dhv = fminf(dhv, SCALE_CLAMP);
  float pcx = __fadd_rn(__fmul_rn(dx, aw), acx);
  float pcy = __fadd_rn(__fmul_rn(dy, ah), acy);
  float pw = __fmul_rn(expf(dwv), aw);
  float ph = __fmul_rn(expf(dhv), ah);
  float x1 = __fsub_rn(pcx, 0.5f*pw), y1 = __fsub_rn(pcy, 0.5f*ph);
  float x2 = __fadd_rn(pcx, 0.5f*pw), y2 = __fadd_rn(pcy, 0.5f*ph);
  x1 = fminf(fmaxf(x1, 0.f), 1024.f);
  y1 = fminf(fmaxf(y1, 0.f), 1024.f);
  x2 = fminf(fmaxf(x2, 0.f), 1024.f);
  y2 = fminf(fmaxf(y2, 0.f), 1024.f);
  float* cbp = cboxes + ((long)n*MCAND + slot)*4;
  cbp[0]=x1; cbp[1]=y1; cbp[2]=x2; cbp[3]=y2;
  cscores[(long)n*MCAND + slot] = sc;
}

// ---------------- top-k kernels ----------------
__global__ void init_ctl(unsigned* ctl) {
  for (int i = threadIdx.x; i < CTL_SIZE; i += 256) ctl[i] = 0;
  __syncthreads();
  if (threadIdx.x < 6) ctl[C_KCUR + threadIdx.x] = 6000;
  if (threadIdx.x < 2) ctl[N_THRPREV + threadIdx.x] = 0xFFFFFFFFu;
}

__global__ __launch_bounds__(256) void tk_hist(const float* __restrict__ scores,
                                               unsigned* ctl, int pass) {
  int t = blockIdx.y; int lvl = t >> 1, n = t & 1;
  int M = LM[lvl]; long base = (long)n*ATOT + LBASE[lvl];
  __shared__ unsigned h[256];
  h[threadIdx.x] = 0;
  __syncthreads();
  unsigned prefix = ctl[C_PRE + t];
  int shift = 24 - 8*pass;
  for (int i = blockIdx.x*256 + threadIdx.x; i < M; i += gridDim.x*256) {
    unsigned key = fkey(scores[base + i]);
    if (pass == 0 || (key >> (shift+8)) == prefix)
      atomicAdd(&h[(key >> shift) & 255], 1u);
  }
  __syncthreads();
  if (h[threadIdx.x]) atomicAdd(&ctl[C_GH + t*256 + threadIdx.x], h[threadIdx.x]);
}

__global__ __launch_bounds__(256) void tk_pick(unsigned* ctl) {
  int t = blockIdx.x;
  if (threadIdx.x == 0) {
    unsigned kcur = ctl[C_KCUR + t];
    int digit = 0;
    for (int d = 255; d >= 0; --d) {
      unsigned c = ctl[C_GH + t*256 + d];
      if (kcur <= c) { digit = d; break; }
      kcur -= c;
    }
    ctl[C_KCUR + t] = kcur;
    ctl[C_PRE + t] = (ctl[C_PRE + t] << 8) | (unsigned)digit;
  }
  __syncthreads();
  ctl[C_GH + t*256 + threadIdx.x] = 0;
}

__global__ __launch_bounds__(256) void tk_compact(const float* __restrict__ scores,
    const float* __restrict__ comb, unsigned* ctl, float* cboxes, float* cscores) {
  int t = blockIdx.y; int lvl = t >> 1, n = t & 1;
  int M = LM[lvl]; long base = (long)n*ATOT + LBASE[lvl];
  unsigned thr = ctl[C_PRE + t];
  for (int i = blockIdx.x*256 + threadIdx.x; i < M; i += gridDim.x*256) {
    unsigned key = fkey(scores[base + i]);
    if (key > thr) {
      unsigned p = atomicAdd(&ctl[C_CNT + t], 1u);
      if (p < 6000u) decode_store(n, lvl, i, CBASE[lvl] + (int)p, comb, cboxes, cscores);
    } else if (key == thr) {
      unsigned p = atomicAdd(&ctl[C_TIE + t], 1u);
      if (p < 1024u) ctl[C_TIEIDX + t*1024 + p] = (unsigned)i;
    }
  }
}

__global__ void tk_finalize(const float* __restrict__ comb, unsigned* ctl,
                            float* cboxes, float* cscores) {
  int t = blockIdx.x; int lvl = t >> 1, n = t & 1;
  if (threadIdx.x != 0) return;
  int cnt = (int)ctl[C_CNT + t]; if (cnt > 6000) cnt = 6000;
  int need = 6000 - cnt;
  int tc = (int)ctl[C_TIE + t]; if (tc > 1024) tc = 1024;
  unsigned* tb = &ctl[C_TIEIDX + t*1024];
  for (int s = 0; s < need; ++s) {
    unsigned mn = 0xFFFFFFFFu; int mi = -1;
    for (int q = 0; q < tc; ++q) { if (tb[q] < mn) { mn = tb[q]; mi = q; } }
    int slot = CBASE[lvl] + cnt + s;
    if (mi >= 0) {
      tb[mi] = 0xFFFFFFFFu;
      decode_store(n, lvl, (int)mn, slot, comb, cboxes, cscores);
    } else {
      float* cbp = cboxes + ((long)n*MCAND + slot)*4;
      cbp[0]=cbp[1]=cbp[2]=cbp[3]=0.f;
      cscores[(long)n*MCAND + slot] = -3.0e38f;
    }
  }
}

__global__ void decode34(const float* __restrict__ comb, float* cboxes, float* cscores) {
  int n = blockIdx.y;
  int e = blockIdx.x*256 + threadIdx.x;
  if (e >= 3840) return;
  if (e < 3072) decode_store(n, 3, e, 18000 + e, comb, cboxes, cscores);
  else          decode_store(n, 4, e - 3072, 21072 + (e - 3072), comb, cboxes, cscores);
}

// =============== NMS: matrix pipeline ===============
__global__ __launch_bounds__(1024) void nms_select(
    const float* __restrict__ cscores, const float* __restrict__ cboxes,
    float* __restrict__ wt, unsigned* ctl) {
  const int n = blockIdx.x;
  if (ctl[N_DONE + n]) return;
  const int tid = threadIdx.x;
  const float* sc = cscores + (long)n*MCAND;
  const float* cb = cboxes + (long)n*MCAND*4;
  u64* skeyG   = ((u64*)(wt + NS_KEY)) + n*RCAP;
  float* boxO  = wt + NS_BOX + n*RCAP*4;
  float* areaG = wt + NS_AREA + n*RCAP;
  __shared__ u64 skey[RCAP];
  __shared__ unsigned hist[256];
  __shared__ unsigned sS[8];
  unsigned thrPrev = ctl[N_THRPREV + n];
  unsigned prefix = 0, kcur = RCAP;
  for (int pass = 0; pass < 4; ++pass) {
    if (tid < 256) hist[tid] = 0;
    __syncthreads();
    int shift = 24 - 8*pass;
    for (int i = tid; i < MCAND; i += 1024) {
      unsigned key = fkey(sc[i]);
      if (key < thrPrev && (pass == 0 || (key >> (shift+8)) == prefix))
        atomicAdd(&hist[(key >> shift) & 255], 1u);
    }
    __syncthreads();
    if (tid == 0) {
      if (pass == 0) { unsigned s = 0; for (int d = 0; d < 256; ++d) s += hist[d]; sS[2] = s; }
      if (sS[2] > RCAP) {
        unsigned kc = kcur; int digit = 0;
        for (int d = 255; d >= 0; --d) {
          unsigned c = hist[d];
          if (kc <= c) { digit = d; break; }
          kc -= c;
        }
        kcur = kc;
        prefix = (prefix << 8) | (unsigned)digit;
        sS[4] = prefix;
      } else sS[4] = 0;
    }
    __syncthreads();
    prefix = sS[4];
    if (sS[2] <= RCAP) break;
  }
  unsigned thr = (sS[2] <= RCAP) ? 0u : sS[4];
  if (tid == 0) sS[0] = 0;
  for (int i = tid; i < RCAP; i += 1024) skey[i] = 0;
  __syncthreads();
  for (int i = tid; i < MCAND; i += 1024) {
    unsigned key = fkey(sc[i]);
    if (key < thrPrev && key >= thr) {
      unsigned p = atomicAdd(&sS[0], 1u);
      if (p < RCAP) skey[p] = ((u64)key << 32) | (unsigned)(~i);
    }
  }
  __syncthreads();
  unsigned scnt = sS[0] > RCAP ? RCAP : sS[0];
  for (int kk = 2; kk <= RCAP; kk <<= 1) {
    for (int jj = kk >> 1; jj > 0; jj >>= 1) {
      for (int i = tid; i < RCAP; i += 1024) {
        int ixj = i ^ jj;
        if (ixj > i) {
          u64 a = skey[i], b = skey[ixj];
          bool up = ((i & kk) == 0);
          if ((a < b) == up) { skey[i] = b; skey[ixj] = a; }
        }
      }
      __syncthreads();
    }
  }
  for (int s = tid; s < RCAP; s += 1024) {
    u64 v = skey[s];
    skeyG[s] = v;
    float x1=0.f,y1=0.f,x2=0.f,y2=0.f,ar=0.f;
    if (v) {
      int idx = (int)(~(unsigned)v);
      float off = 2000.f * (float)lvl_of(idx);
      x1 = cb[idx*4+0] + off; y1 = cb[idx*4+1] + off;
      x2 = cb[idx*4+2] + off; y2 = cb[idx*4+3] + off;
      ar = (x2-x1)*(y2-y1);
    }
    boxO[s*4+0]=x1; boxO[s*4+1]=y1; boxO[s*4+2]=x2; boxO[s*4+3]=y2;
    areaG[s]=ar;
  }
  if (tid == 0) {
    ctl[N_SCNT + n] = scnt;
    ctl[N_THRPREV + n] = thr;
    if (thr == 0u) ctl[N_LAST + n] = 1;
    if (scnt == 0) ctl[N_DONE + n] = 1;
  }
}

__global__ __launch_bounds__(256) void nms_matrix(const float* __restrict__ wt_c,
                                                  float* __restrict__ wt, unsigned* ctl) {
  const int n = blockIdx.y;
  if (ctl[N_DONE + n]) return;
  const int bx = blockIdx.x;
  const int i0 = bx * 64;
  const int tid = threadIdx.x;
  const int wv = tid >> 6;
  const int lane = tid & 63;
  const float* boxO  = wt_c + NS_BOX + n*RCAP*4;
  const float* areaG = wt_c + NS_AREA + n*RCAP;
  const float* kbox  = wt_c + NS_KBOX + n*1024*5;
  u64* mask  = ((u64*)(wt + NS_MASK)) + (long)n*RCAP*64;
  u64* diagA = ((u64*)(wt + NS_DIAG)) + n*64*64;
  u64* psupW = ((u64*)(wt + NS_PSUP)) + n*64;
  int kt0 = (int)ctl[N_KEPT + n];
  __shared__ float rb[64][5];
  __shared__ unsigned psw[2];
  if (tid < 2) psw[tid] = 0;
  if (tid < 64) {
    rb[tid][0]=boxO[(i0+tid)*4+0]; rb[tid][1]=boxO[(i0+tid)*4+1];
    rb[tid][2]=boxO[(i0+tid)*4+2]; rb[tid][3]=boxO[(i0+tid)*4+3];
    rb[tid][4]=areaG[i0+tid];
  }
  __syncthreads();
  if (kt0 > 0) {
    for (int rr = 0; rr < 16; ++rr) {
      int il = wv*16 + rr;
      float rx1=rb[il][0], ry1=rb[il][1], rx2=rb[il][2], ry2=rb[il][3], rar=rb[il][4];
      bool s = false;
      for (int k = lane; k < kt0; k += 64) {
        float iou = iou_f(rx1,ry1,rx2,ry2,rar,
                          kbox[k*5+0],kbox[k*5+1],kbox[k*5+2],kbox[k*5+3],kbox[k*5+4]);
        s |= (iou > 0.7f);
      }
      u64 bal = __ballot(s);
      if (lane == 0 && bal) atomicOr(&psw[il>>5], 1u << (il & 31));
    }
  }
  __syncthreads();
  if (tid == 0) psupW[bx] = ((u64)psw[1] << 32) | psw[0];
  for (int w = 0; w < 64; ++w) {
    int cidx = w*64 + lane;
    float cx1=boxO[cidx*4+0], cy1=boxO[cidx*4+1], cx2=boxO[cidx*4+2], cy2=boxO[cidx*4+3];
    float car=areaG[cidx];
    #pragma unroll 4
    for (int rr = 0; rr < 16; ++rr) {
      int il = wv*16 + rr;
      int i = i0 + il;
      float iou = iou_f(rb[il][0],rb[il][1],rb[il][2],rb[il][3],rb[il][4],
                        cx1,cy1,cx2,cy2,car);
      bool bit = (iou > 0.7f) && (cidx > i);
      u64 m = __ballot(bit);
      if (lane == 0) {
        mask[(long)i*64 + w] = m;
        if (w == bx) diagA[bx*64 + il] = m;
      }
    }
  }
}

__global__ __launch_bounds__(64) void nms_scan(
    const float* __restrict__ cscores, const float* __restrict__ cboxes,
    float* __restrict__ wt, unsigned* ctl, float* __restrict__ dout) {
  const int n = blockIdx.x;
  if (ctl[N_DONE + n]) return;
  const int lane = threadIdx.x;
  const float* cb = cboxes + (long)n*MCAND*4;
  u64* skeyG = ((u64*)(wt + NS_KEY)) + n*RCAP;
  const float* boxO  = wt + NS_BOX + n*RCAP*4;
  const float* areaG = wt + NS_AREA + n*RCAP;
  u64* mask  = ((u64*)(wt + NS_MASK)) + (long)n*RCAP*64;
  u64* diagA = ((u64*)(wt + NS_DIAG)) + n*64*64;
  u64* psupW = ((u64*)(wt + NS_PSUP)) + n*64;
  float* kbox = wt + NS_KBOX + n*1024*5;
  float* keepB = dout + KB_OFF + (long)n*4*POSTK;
  float* keepS = dout + KS_OFF + (long)n*POSTK;
  float* keepV = dout + KV_OFF + (long)n*POSTK;
  int scnt = (int)ctl[N_SCNT + n];
  int kt = (int)ctl[N_KEPT + n];
  __shared__ u64 alive[64];
  {
    int rem = scnt - lane*64;
    u64 a = rem >= 64 ? ~0ull : (rem > 0 ? ((1ull << rem) - 1ull) : 0ull);
    alive[lane] = a & ~psupW[lane];
  }
  __syncthreads();
  for (int c = 0; c < 64 && kt < POSTK; ++c) {
    u64 w64 = alive[c];
    if (!w64) continue;
    u64 diag = diagA[c*64 + lane];
    u64 kb = 0;
    while (w64) {
      int b = __ffsll(w64) - 1;
      kb |= (1ull << b);
      w64 &= ~(1ull << b);
      u64 sup = __shfl(diag, b);
      w64 &= ~sup;
      if (++kt >= POSTK) break;
    }
    alive[c] = 0;
    if ((kb >> lane) & 1) {
      int base = kt - (int)__popcll(kb);
      int pos = base + (int)__popcll(kb & ((1ull << lane) - 1ull));
      int s = c*64 + lane;
      u64 v = skeyG[s];
      int idx = (int)(~(unsigned)v);
      keepB[pos*4+0]=cb[idx*4+0]; keepB[pos*4+1]=cb[idx*4+1];
      keepB[pos*4+2]=cb[idx*4+2]; keepB[pos*4+3]=cb[idx*4+3];
      keepS[pos] = unfkey((unsigned)(v >> 32));
      keepV[pos] = 1.f;
      kbox[pos*5+0]=boxO[s*4+0]; kbox[pos*5+1]=boxO[s*4+1];
      kbox[pos*5+2]=boxO[s*4+2]; kbox[pos*5+3]=boxO[s*4+3];
      kbox[pos*5+4]=areaG[s];
    }
    __syncthreads();
    if (kb && lane > c && alive[lane]) {
      u64 acc = 0, m = kb;
      while (m) {
        int b = __ffsll(m) - 1; m &= m - 1;
        acc |= mask[(long)(c*64 + b)*64 + lane];
      }
      if (acc) alive[lane] &= ~acc;
    }
    __syncthreads();
  }
  if (lane == 0) {
    ctl[N_KEPT + n] = (unsigned)kt;
    if (kt >= POSTK || ctl[N_LAST + n]) ctl[N_DONE + n] = 1;
  }
}

__device__ inline u64 shfl_down_u64d(u64 v, int o) {
  unsigned hi = __shfl_down((unsigned)(v >> 32), o);
  unsigned lo = __shfl_down((unsigned)v, o);
  return ((u64)hi << 32) | lo;
}
__global__ __launch_bounds__(1024) void nms_fill(
    const float* __restrict__ cscores, const float* __restrict__ cboxes,
    unsigned* ctl, float* __restrict__ dout) {
  const int n = blockIdx.x;
  const int tid = threadIdx.x;
  const int lane = tid & 63;
  const int wid = tid >> 6;
  const float* sc = cscores + (long)n*MCAND;
  const float* cb = cboxes + (long)n*MCAND*4;
  float* keepB = dout + KB_OFF + (long)n*4*POSTK;
  float* keepS = dout + KS_OFF + (long)n*POSTK;
  float* keepV = dout + KV_OFF + (long)n*POSTK;
  __shared__ u64 wred[16];
  __shared__ u64 sBest;
  u64 best = 0;
  for (int i = tid; i < 6000; i += 1024) {
    u64 v = ((u64)fkey(sc[i]) << 32) | (unsigned)(~i);
    if (v > best) best = v;
  }
  for (int o = 32; o > 0; o >>= 1) {
    u64 ov = shfl_down_u64d(best, o);
    if (ov > best) best = ov;
  }
  if (lane == 0) wred[wid] = best;
  __syncthreads();
  if (tid == 0) {
    u64 b = 0;
    for (int i = 0; i < 16; ++i) if (wred[i] > b) b = wred[i];
    sBest = b;
  }
  __syncthreads();
  int kt = (int)ctl[N_KEPT + n];
  int bidx = (int)(~(unsigned)sBest);
  float b0 = cb[bidx*4+0], b1 = cb[bidx*4+1], b2 = cb[bidx*4+2], b3 = cb[bidx*4+3];
  float bsc = sc[bidx];
  for (int s2 = kt + tid; s2 < POSTK; s2 += 1024) {
    keepB[s2*4+0]=b0; keepB[s2*4+1]=b1; keepB[s2*4+2]=b2; keepB[s2*4+3]=b3;
    keepS[s2] = bsc; keepV[s2] = 0.f;
  }
}

// ---------------- launcher ----------------
extern "C" void kernel_launch(void* const* d_in, const int* in_sizes, int n_in,
                              void* d_out, int out_size, void* d_ws, size_t ws_size,
                              hipStream_t stream) {
  const float* feats[5];
  for (int i = 0; i < 5; ++i) feats[i] = (const float*)d_in[i];
  const float* conv_w  = (const float*)d_in[5];
  const float* conv_b  = (const float*)d_in[6];
  const float* obj_w   = (const float*)d_in[7];
  const float* obj_b   = (const float*)d_in[8];
  const float* delta_w = (const float*)d_in[9];
  const float* delta_b = (const float*)d_in[10];
  float* out = (float*)d_out;
  float* ws = (float*)d_ws;

  const bool big = ws_size >= (size_t)FT_END * 4ull;
  float *t, *scores, *cboxes, *cscores, *wp;
  unsigned* ctl;
  if (big) {
    t = ws + FT_T; scores = ws + FT_SC; cboxes = ws + FT_CB;
    cscores = ws + FT_CS; ctl = (unsigned*)(ws + FT_CTL); wp = ws + FT_WP;
  } else {
    t = ws + WS_T; scores = ws + WS_SC; cboxes = ws + WS_CB;
    cscores = ws + WS_CS; ctl = (unsigned*)(ws + WS_CTL); wp = ws + WS_WP;
  }

  static const int LWh[5]    = {256,128,64,32,16};
  static const int LBASEh[5] = {0,196608,245760,258048,261120};

  wprep_mfma<<<dim3(2304), dim3(256), 0, stream>>>(conv_w, (f16*)wp);
  init_ctl<<<dim3(1), dim3(256), 0, stream>>>(ctl);

  if (big) {
    conv_big<<<dim3(682), dim3(512), 0, stream>>>(
        feats[0], feats[1], feats[2], feats[3], feats[4], (const f16*)wp, conv_b,
        obj_w, obj_b, delta_w, delta_b, out, scores);
  } else {
    for (int n = 0; n < 2; ++n) {
      for (int lvl = 0; lvl < 5; ++lvl) {
        int H = LWh[lvl], W = LWh[lvl], HW = H*W;
        conv_lvl_mfma<<<dim3(W/16, H/8), dim3(256), 0, stream>>>(
            feats[lvl] + (long)n*256*HW, (const f16*)wp, conv_b, t, H, W);
        int hb = (HW + 1023) / 1024;
        heads1x1<<<dim3(hb), dim3(256), 0, stream>>>(
            t, obj_w, obj_b, delta_w, delta_b, out, scores, HW, LBASEh[lvl], n);
      }
    }
  }

  for (int p = 0; p < 4; ++p) {
    tk_hist<<<dim3(48,6), dim3(256), 0, stream>>>(scores, ctl, p);
    tk_pick<<<dim3(6), dim3(256), 0, stream>>>(ctl);
  }
  tk_compact<<<dim3(48,6), dim3(256), 0, stream>>>(scores, out, ctl, cboxes, cscores);
  tk_finalize<<<dim3(6), dim3(64), 0, stream>>>(out, ctl, cboxes, cscores);
  decode34<<<dim3(15,2), dim3(256), 0, stream>>>(out, cboxes, cscores);
  for (int b = 0; b < 6; ++b) {
    nms_select<<<dim3(2), dim3(1024), 0, stream>>>(cscores, cboxes, t, ctl);
    nms_matrix<<<dim3(64,2), dim3(256), 0, stream>>>(t, t, ctl);
    nms_scan<<<dim3(2), dim3(64), 0, stream>>>(cscores, cboxes, t, ctl, out);
  }
  nms_fill<<<dim3(2), dim3(1024), 0, stream>>>(cscores, cboxes, ctl, out);
}

// Round 7
// 1487.092 us; speedup vs baseline: 3.5696x; 1.1031x over previous
//
#include <hip/hip_runtime.h>
#include <math.h>

// ---------------- problem constants ----------------
#define ATOT 261888          // sum over levels of H*W*3
#define MCAND 21840          // 6000+6000+6000+3072+768 candidates per image
#define POSTK 1000
#define CMB (2*ATOT*5)       // combined output floats = 2618880
#define KB_OFF CMB           // keep_boxes offset in d_out
#define KS_OFF (CMB+8000)    // keep_scores
#define KV_OFF (CMB+10000)   // valid
#define SCALE_CLAMP 4.135166556742356f
#define RCAP 4096

typedef unsigned long long u64;

// ---------------- fallback (small-ws) layout, float units ----------------
#define WS_T   0
#define WS_SC  (256*65536)
#define WS_CB  (WS_SC + 2*ATOT)
#define WS_CS  (WS_CB + 2*MCAND*4)
#define WS_CTL (WS_CS + 2*MCAND)

// ctl indices (u32)
#define C_PRE 0
#define C_KCUR 6
#define C_CNT 12
#define C_TIE 18
#define N_THRPREV 24
#define N_KEPT 26
#define N_DONE 28
#define N_SCNT 30
#define N_LAST 32
#define C_GH 40
#define C_TIEIDX (C_GH + 6*256)
#define CTL_SIZE (C_TIEIDX + 6*1024)
#define WS_WP  (WS_CTL + CTL_SIZE)

// ---------------- fused (big-ws) layout, float units ----------------
#define FT_T   0
#define FT_TSZ 22347776                 // 256 * 87296 (all levels, one image)
#define FT_SC  22347776
#define FT_CB  (FT_SC + 2*ATOT)         // 22871552
#define FT_CS  (FT_CB + 2*MCAND*4)      // 23046272
#define FT_CTL (FT_CS + 2*MCAND)        // 23089952
#define FT_WP  (FT_CTL + CTL_SIZE)      // 23097672
#define FT_END (FT_WP + 589824)         // 23687496 floats = 94,749,984 B

// ---- NMS scratch inside the (dead-by-then) t buffer ----
#define NS_KEY  0
#define NS_BOX  16384
#define NS_AREA 49152
#define NS_DIAG 57344
#define NS_PSUP 73728
#define NS_KBOX 73984
#define NS_MASK 84224                   // end 1,132,800 floats

__device__ const int LW[5]    = {256,128,64,32,16};
__device__ const int LM[5]    = {196608,49152,12288,3072,768};
__device__ const int LBASE[5] = {0,196608,245760,258048,261120};
__device__ const int LSTR[5]  = {4,8,16,32,64};
__device__ const int LSZ[5]   = {32,64,128,256,512};
__device__ const int CBASE[5] = {0,6000,12000,18000,21072};
__device__ const int TOFF[5]  = {0,16777216,20971520,22020096,22282240}; // 256*cumHW

__device__ inline unsigned fkey(float f) {
  unsigned u = __float_as_uint(f);
  return u ^ (unsigned)(((int)u >> 31) | 0x80000000);
}
__device__ inline float unfkey(unsigned k) {
  unsigned u = (k & 0x80000000u) ? (k ^ 0x80000000u) : ~k;
  return __uint_as_float(u);
}
__device__ inline int lvl_of(int idx) {
  return idx < 6000 ? 0 : idx < 12000 ? 1 : idx < 18000 ? 2 : idx < 21072 ? 3 : 4;
}
__device__ inline float iou_f(float ax1,float ay1,float ax2,float ay2,float aar,
                              float bx1,float by1,float bx2,float by2,float bar) {
  float ix1 = fmaxf(ax1,bx1), iy1 = fmaxf(ay1,by1);
  float ix2 = fminf(ax2,bx2), iy2 = fminf(ay2,by2);
  float inter = fmaxf(ix2-ix1,0.f) * fmaxf(iy2-iy1,0.f);
  return inter / (aar + bar - inter + 1e-9f);
}

// =========================================================================
// MFMA conv: f16 hi/lo split (inputs & weights pre-scaled by 2^11; epilogue
// rescales by 2^-22). 3 MFMAs (hh, lh, hl) per nominal fp32 product.
// Big path: 682 blocks x 512 threads (8 waves, 2/SIMD, 256 unified
// regs/wave — DO NOT raise block size: 1024thr forces 128 regs/wave and
// spills acc to scratch, round-5 fiasco).
// Round-7: epilogue 'part' layout reordered (cg innermost, 244-float pad)
// — the c2-summed read previously strided 15,360 B == 0 mod 128 (all-bank
// alias, the real source of SQ_LDS_BANK_CONFLICT 2.5e7).
// =========================================================================
typedef _Float16 f16;
typedef _Float16 f16x2 __attribute__((ext_vector_type(2)));
typedef _Float16 f16x8 __attribute__((ext_vector_type(8)));
typedef float f32x4 __attribute__((ext_vector_type(4)));

#define MFMA16(a,b,c) __builtin_amdgcn_mfma_f32_16x16x32_f16(a,b,c,0,0,0)
#define AST 40            // fallback-path padded channel stride (f16)
#define WHALF 589824      // f16 elements per half (hi block / lo block)

// weight prep: conv_w[oc][ci][kh][kw] fp32 ->
//   wsp[h][t][kc][ks][oc][j] f16, h in {hi,lo}, ci = kc*32+ks*8+j, t = kh*3+kw
// block 2304 additionally initializes ctl (merged init_ctl, -1 launch).
__global__ __launch_bounds__(256) void wprep_mfma(const float* __restrict__ wgt,
                                                  f16* __restrict__ wsp,
                                                  unsigned* __restrict__ ctl) {
  if (blockIdx.x == 2304) {
    for (int i = threadIdx.x; i < CTL_SIZE; i += 256) ctl[i] = 0;
    __syncthreads();
    if (threadIdx.x < 6) ctl[C_KCUR + threadIdx.x] = 6000;
    if (threadIdx.x < 2) ctl[N_THRPREV + threadIdx.x] = 0xFFFFFFFFu;
    return;
  }
  int o = blockIdx.x*256 + threadIdx.x;
  if (o >= WHALF) return;
  int j  = o & 7;
  int oc = (o >> 3) & 255;
  int ks = (o >> 11) & 3;
  int kc = (o >> 13) & 7;
  int t  = o >> 16;
  int ci = kc*32 + ks*8 + j;
  float v = wgt[(oc*256 + ci)*9 + t] * 2048.f;
  f16 hi = (f16)v;
  f16 lo = (f16)(v - (float)hi);
  wsp[o] = hi;
  wsp[WHALF + o] = lo;
}

// ---------------- BIG-TILE fused conv+heads (both images, one dispatch) ----
// block: 16x16 px, 8 waves (rg 0/1 rows, cg 0..3 oc-slices of 64).
// LDS layout: A[(ks*324 + p)*8 + j], ci = ks*8 + j within 32-chan chunk.
#define ABUF2 10368       // f16 per Ah (or Al) block = 1296*8
#define SBUF2 20736       // f16 per full buffer (Ah+Al)
#define PREG 244          // padded floats per (rg,mt,ks) partial group

__global__ __launch_bounds__(512,2) void conv_big(
    const float* __restrict__ f0, const float* __restrict__ f1,
    const float* __restrict__ f2, const float* __restrict__ f3,
    const float* __restrict__ f4, const f16* __restrict__ wsp,
    const float* __restrict__ bias,
    const float* __restrict__ ow, const float* __restrict__ obp,
    const float* __restrict__ dwp, const float* __restrict__ dbp,
    float* __restrict__ comb, float* __restrict__ scores) {
  __shared__ __align__(16) char SBc[82944];    // 2 buffers x 41472 B
  __shared__ float wHs[15][256];
  const int tid = threadIdx.x;

  // block geometry: id -> (image, level, tile). 341 blocks per image.
  int id = blockIdx.x;
  int n = (id >= 341) ? 1 : 0;
  int rem = id - n*341;
  int lvl, tile;
  if (rem < 256)      { lvl = 0; tile = rem; }
  else if (rem < 320) { lvl = 1; tile = rem - 256; }
  else if (rem < 336) { lvl = 2; tile = rem - 320; }
  else if (rem < 340) { lvl = 3; tile = rem - 336; }
  else                { lvl = 4; tile = 0; }
  const int W = LW[lvl], H = W, HW = W*W;
  const int tw = W >> 4;
  const int ty0 = tile / tw, tx0 = tile - ty0*tw;
  const int x0 = tx0*16, y0 = ty0*16;
  const int lbase = LBASE[lvl];
  const float* in = (lvl==0?f0:lvl==1?f1:lvl==2?f2:lvl==3?f3:f4) + (long)n*256*HW;

  const int wv   = tid >> 6;
  const int lane = tid & 63;
  const int l15  = lane & 15;
  const int ks   = lane >> 4;
  const int rg   = wv >> 2;      // row group: rows rg*8 .. rg*8+7
  const int cg   = wv & 3;       // oc slice:  oc cg*64 .. cg*64+63

  // stage head weights once (read in epilogue, after barriers)
  for (int i = tid; i < 768; i += 512)  wHs[i>>8][i&255] = ow[i];
  for (int i = tid; i < 3072; i += 512) wHs[3+(i>>8)][i&255] = dwp[i];

  // ---- per-thread staging geometry (loop-invariant over kc) ----
  int ubo0, ubo1, ubo2; bool uin0, uin1, uin2;
  {
    int u = tid;
    int ksu = u / 324, pu = u - ksu*324;
    int hy = pu/18, hx = pu - hy*18;
    int gy = y0 + hy - 1, gx = x0 + hx - 1;
    uin0 = (gy>=0) & (gy<H) & (gx>=0) & (gx<W);
    ubo0 = ksu*8*HW + min(max(gy,0),H-1)*W + min(max(gx,0),W-1);
  }
  {
    int u = tid + 512;
    int ksu = u / 324, pu = u - ksu*324;
    int hy = pu/18, hx = pu - hy*18;
    int gy = y0 + hy - 1, gx = x0 + hx - 1;
    uin1 = (gy>=0) & (gy<H) & (gx>=0) & (gx<W);
    ubo1 = ksu*8*HW + min(max(gy,0),H-1)*W + min(max(gx,0),W-1);
  }
  const bool has2 = tid < 272;
  {
    int u = has2 ? tid + 1024 : 0;
    int ksu = u / 324, pu = u - ksu*324;
    int hy = pu/18, hx = pu - hy*18;
    int gy = y0 + hy - 1, gx = x0 + hx - 1;
    uin2 = (gy>=0) & (gy<H) & (gx>=0) & (gx<W);
    ubo2 = ksu*8*HW + min(max(gy,0),H-1)*W + min(max(gx,0),W-1);
  }

  float sv0[8], sv1[8], sv2[8];
  auto stage = [&](int kc, int b) {
    const float* q = in + (size_t)(kc*32)*HW;
    #pragma unroll
    for (int j = 0; j < 8; ++j) sv0[j] = q[ubo0 + j*HW];
    #pragma unroll
    for (int j = 0; j < 8; ++j) sv1[j] = q[ubo1 + j*HW];
    if (has2) {
      #pragma unroll
      for (int j = 0; j < 8; ++j) sv2[j] = q[ubo2 + j*HW];
    }
    f16* AhB = (f16*)SBc + b*SBUF2;
    f16* AlB = AhB + ABUF2;
    f16x8 vh, vl;
    #pragma unroll
    for (int j = 0; j < 8; ++j) {
      float v = uin0 ? sv0[j]*2048.f : 0.f;
      f16 h = (f16)v; vh[j] = h; vl[j] = (f16)(v - (float)h);
    }
    *(f16x8*)&AhB[tid*8] = vh;
    *(f16x8*)&AlB[tid*8] = vl;
    #pragma unroll
    for (int j = 0; j < 8; ++j) {
      float v = uin1 ? sv1[j]*2048.f : 0.f;
      f16 h = (f16)v; vh[j] = h; vl[j] = (f16)(v - (float)h);
    }
    *(f16x8*)&AhB[(tid+512)*8] = vh;
    *(f16x8*)&AlB[(tid+512)*8] = vl;
    if (has2) {
      #pragma unroll
      for (int j = 0; j < 8; ++j) {
        float v = uin2 ? sv2[j]*2048.f : 0.f;
        f16 h = (f16)v; vh[j] = h; vl[j] = (f16)(v - (float)h);
      }
      *(f16x8*)&AhB[(tid+1024)*8] = vh;
      *(f16x8*)&AlB[(tid+1024)*8] = vl;
    }
  };

  const f32x4 vzero = {0.f, 0.f, 0.f, 0.f};
  f32x4 acc[8][4];
  #pragma unroll
  for (int mt = 0; mt < 8; ++mt)
    #pragma unroll
    for (int nt = 0; nt < 4; ++nt) acc[mt][nt] = vzero;

  stage(0, 0);
  __syncthreads();

  for (int kc = 0; kc < 8; ++kc) {
    const int b = kc & 1;
    if (kc < 7) stage(kc + 1, b ^ 1);    // writes other buffer: no conflict
    const f16* AhB = (const f16*)SBc + b*SBUF2;
    const f16* AlB = AhB + ABUF2;
    for (int t = 0; t < 9; ++t) {
      const int tyk = t / 3, txk = t - (t/3)*3;
      const f16* wb = wsp + (((t*8 + kc)*4 + ks)*256 + cg*64 + l15)*8;
      f16x8 Bh0 = *(const f16x8*)(wb);
      f16x8 Bh1 = *(const f16x8*)(wb + 128);
      f16x8 Bh2 = *(const f16x8*)(wb + 256);
      f16x8 Bh3 = *(const f16x8*)(wb + 384);
      f16x8 Bl0 = *(const f16x8*)(wb + WHALF);
      f16x8 Bl1 = *(const f16x8*)(wb + WHALF + 128);
      f16x8 Bl2 = *(const f16x8*)(wb + WHALF + 256);
      f16x8 Bl3 = *(const f16x8*)(wb + WHALF + 384);
      #pragma unroll
      for (int mt = 0; mt < 8; ++mt) {
        const int p = (rg*8 + mt + tyk)*18 + l15 + txk;
        f16x8 Af = *(const f16x8*)&AhB[(ks*324 + p)*8];
        f16x8 Ae = *(const f16x8*)&AlB[(ks*324 + p)*8];
        acc[mt][0] = MFMA16(Af, Bh0, acc[mt][0]);
        acc[mt][1] = MFMA16(Af, Bh1, acc[mt][1]);
        acc[mt][2] = MFMA16(Af, Bh2, acc[mt][2]);
        acc[mt][3] = MFMA16(Af, Bh3, acc[mt][3]);
        acc[mt][0] = MFMA16(Ae, Bh0, acc[mt][0]);
        acc[mt][1] = MFMA16(Ae, Bh1, acc[mt][1]);
        acc[mt][2] = MFMA16(Ae, Bh2, acc[mt][2]);
        acc[mt][3] = MFMA16(Ae, Bh3, acc[mt][3]);
        acc[mt][0] = MFMA16(Af, Bl0, acc[mt][0]);
        acc[mt][1] = MFMA16(Af, Bl1, acc[mt][1]);
        acc[mt][2] = MFMA16(Af, Bl2, acc[mt][2]);
        acc[mt][3] = MFMA16(Af, Bl3, acc[mt][3]);
      }
    }
    __syncthreads();                     // buffer b free; b^1 staged complete
  }

  // ---- fused heads epilogue (no t-buffer) ----
  // part layout: [bg = (rg*8+mt)*4+ks][j*16 + cg*4 + comp], PREG=244 pad.
  // cg (the summed dim) is innermost at 16B: the 4-term read walks
  // consecutive bank groups; bg stride 976B == 80 mod 128 de-aliases k2/mt.
  const float rs = 1.f / 4194304.f;      // 2^-22, exact
  float* part = (float*)SBc;             // staging dead; 64*244*4 = 62,464 B
  float bb[4];
  #pragma unroll
  for (int nt = 0; nt < 4; ++nt) bb[nt] = bias[cg*64 + nt*16 + l15];

  #pragma unroll
  for (int mt = 0; mt < 8; ++mt) {
    f32x4 y[4];
    #pragma unroll
    for (int nt = 0; nt < 4; ++nt) {
      f32x4 a = acc[mt][nt];
      y[nt][0] = fmaxf(a[0]*rs + bb[nt], 0.f);
      y[nt][1] = fmaxf(a[1]*rs + bb[nt], 0.f);
      y[nt][2] = fmaxf(a[2]*rs + bb[nt], 0.f);
      y[nt][3] = fmaxf(a[3]*rs + bb[nt], 0.f);
    }
    #pragma unroll
    for (int j = 0; j < 15; ++j) {
      float w0 = wHs[j][cg*64 + l15];
      float w1 = wHs[j][cg*64 + 16 + l15];
      float w2 = wHs[j][cg*64 + 32 + l15];
      float w3 = wHs[j][cg*64 + 48 + l15];
      f32x4 p4;
      p4[0] = y[0][0]*w0 + y[1][0]*w1 + y[2][0]*w2 + y[3][0]*w3;
      p4[1] = y[0][1]*w0 + y[1][1]*w1 + y[2][1]*w2 + y[3][1]*w3;
      p4[2] = y[0][2]*w0 + y[1][2]*w1 + y[2][2]*w2 + y[3][2]*w3;
      p4[3] = y[0][3]*w0 + y[1][3]*w1 + y[2][3]*w2 + y[3][3]*w3;
      #pragma unroll
      for (int m = 1; m < 16; m <<= 1) {   // reduce the 16 oc-lanes
        p4[0] += __shfl_xor(p4[0], m);
        p4[1] += __shfl_xor(p4[1], m);
        p4[2] += __shfl_xor(p4[2], m);
        p4[3] += __shfl_xor(p4[3], m);
      }
      if (l15 == 0) {
        int bg = (rg*8 + mt)*4 + ks;
        float* pp = part + bg*PREG + j*16 + cg*4;
        pp[0] = p4[0]; pp[1] = p4[1]; pp[2] = p4[2]; pp[3] = p4[3];
      }
    }
  }
  __syncthreads();
  if (tid < 256) {
    int rg2 = tid >> 7, mt = (tid >> 4) & 7, xi = tid & 15;
    int k2 = xi >> 2, xj = xi & 3;
    int bg2 = (rg2*8 + mt)*4 + k2;
    const float* pr = part + bg2*PREG + xj;
    float v[15];
    #pragma unroll
    for (int j = 0; j < 15; ++j) {
      // sum the 4 cg partials in the same order as before (bit-identical)
      float s = pr[j*16] + pr[j*16 + 4];
      s += pr[j*16 + 8];
      s += pr[j*16 + 12];
      v[j] = s;
    }
    int pos = (y0 + rg2*8 + mt)*W + x0 + xi;
    long base = (long)n*ATOT + lbase + (long)pos*3;
    #pragma unroll
    for (int a = 0; a < 3; ++a) {
      float lg = v[a] + obp[a];
      comb[(base+a)*5] = lg;
      scores[(long)n*ATOT + lbase + pos*3 + a] = lg;
      #pragma unroll
      for (int q = 0; q < 4; ++q)
        comb[(base+a)*5 + 1 + q] = v[3 + a*4 + q] + dbp[a*4+q];
    }
  }
}

// ---------------- fallback conv (small-ws): 16x8 tile, writes t ----------
__global__ __launch_bounds__(256,2) void conv_lvl_mfma(
    const float* __restrict__ in, const f16* __restrict__ wsp,
    const float* __restrict__ bias, float* __restrict__ outp, int H, int W) {
  __shared__ __align__(16) char SBc[28800];
  f16* Ah = (f16*)SBc;
  f16* Al = (f16*)(SBc + 14400);
  const int tid  = threadIdx.x;
  const int wv   = tid >> 6;
  const int lane = tid & 63;
  const int l15  = lane & 15;
  const int ks   = lane >> 4;
  const int HW   = H * W;
  const int x0 = blockIdx.x*16, y0 = blockIdx.y*8;

  const f32x4 vzero = {0.f, 0.f, 0.f, 0.f};
  f32x4 acc[8][4];
  #pragma unroll
  for (int mt = 0; mt < 8; ++mt)
    #pragma unroll
    for (int nt = 0; nt < 4; ++nt) acc[mt][nt] = vzero;

  for (int kc = 0; kc < 8; ++kc) {
    __syncthreads();
    for (int i = tid; i < 2880; i += 256) {
      int cp = i / 180; int p = i - cp*180;
      int hy = p / 18, hx = p - hy*18;
      int gy = y0 + hy - 1, gx = x0 + hx - 1;
      float v0 = 0.f, v1 = 0.f;
      if (gy >= 0 && gy < H && gx >= 0 && gx < W) {
        const float* q = in + (long)(kc*32 + 2*cp)*HW + gy*W + gx;
        v0 = q[0] * 2048.f;
        v1 = q[HW] * 2048.f;
      }
      f16 h0 = (f16)v0, h1 = (f16)v1;
      f16 e0 = (f16)(v0 - (float)h0), e1 = (f16)(v1 - (float)h1);
      f16x2 ph; ph[0] = h0; ph[1] = h1;
      f16x2 pl; pl[0] = e0; pl[1] = e1;
      *(f16x2*)&Ah[p*AST + 2*cp] = ph;
      *(f16x2*)&Al[p*AST + 2*cp] = pl;
    }
    __syncthreads();
    for (int t = 0; t < 9; ++t) {
      const int tyk = t / 3, txk = t - (t/3)*3;
      const f16* wb = wsp + (((t*8 + kc)*4 + ks)*256 + wv*64 + l15)*8;
      f16x8 Bh0 = *(const f16x8*)(wb);
      f16x8 Bh1 = *(const f16x8*)(wb + 128);
      f16x8 Bh2 = *(const f16x8*)(wb + 256);
      f16x8 Bh3 = *(const f16x8*)(wb + 384);
      f16x8 Bl0 = *(const f16x8*)(wb + WHALF);
      f16x8 Bl1 = *(const f16x8*)(wb + WHALF + 128);
      f16x8 Bl2 = *(const f16x8*)(wb + WHALF + 256);
      f16x8 Bl3 = *(const f16x8*)(wb + WHALF + 384);
      #pragma unroll
      for (int mt = 0; mt < 8; ++mt) {
        const int p = (mt + tyk)*18 + l15 + txk;
        f16x8 Af = *(const f16x8*)&Ah[p*AST + ks*8];
        f16x8 Ae = *(const f16x8*)&Al[p*AST + ks*8];
        acc[mt][0] = MFMA16(Af, Bh0, acc[mt][0]);
        acc[mt][1] = MFMA16(Af, Bh1, acc[mt][1]);
        acc[mt][2] = MFMA16(Af, Bh2, acc[mt][2]);
        acc[mt][3] = MFMA16(Af, Bh3, acc[mt][3]);
        acc[mt][0] = MFMA16(Ae, Bh0, acc[mt][0]);
        acc[mt][1] = MFMA16(Ae, Bh1, acc[mt][1]);
        acc[mt][2] = MFMA16(Ae, Bh2, acc[mt][2]);
        acc[mt][3] = MFMA16(Ae, Bh3, acc[mt][3]);
        acc[mt][0] = MFMA16(Af, Bl0, acc[mt][0]);
        acc[mt][1] = MFMA16(Af, Bl1, acc[mt][1]);
        acc[mt][2] = MFMA16(Af, Bl2, acc[mt][2]);
        acc[mt][3] = MFMA16(Af, Bl3, acc[mt][3]);
      }
    }
  }
  const float rs = 1.f / 4194304.f;
  #pragma unroll
  for (int nt = 0; nt < 4; ++nt) {
    int oc = wv*64 + nt*16 + l15;
    float bbv = bias[oc];
    #pragma unroll
    for (int mt = 0; mt < 8; ++mt) {
      f32x4 a = acc[mt][nt];
      float4 v;
      v.x = fmaxf(a[0]*rs + bbv, 0.f);
      v.y = fmaxf(a[1]*rs + bbv, 0.f);
      v.z = fmaxf(a[2]*rs + bbv, 0.f);
      v.w = fmaxf(a[3]*rs + bbv, 0.f);
      *(float4*)&outp[(long)oc*HW + (y0+mt)*W + x0 + ks*4] = v;
    }
  }
}

// ---------------- 1x1 heads (fallback path only) ----------------
__global__ __launch_bounds__(256) void heads1x1(
    const float* __restrict__ t, const float* __restrict__ ow, const float* __restrict__ ob,
    const float* __restrict__ dw, const float* __restrict__ db,
    float* __restrict__ comb, float* __restrict__ scores, int HW, int lbase, int n) {
  __shared__ float wS[15][256];
  const int tid = threadIdx.x;
  for (int i = tid; i < 3*256; i += 256) wS[i>>8][i&255] = ow[i];
  for (int i = tid; i < 12*256; i += 256) wS[3+(i>>8)][i&255] = dw[i];
  __syncthreads();
  int p0 = (blockIdx.x*256 + threadIdx.x)*4;
  if (p0 >= HW) return;
  float acc[15][4] = {};
  for (int c = 0; c < 256; ++c) {
    float4 v = *(const float4*)&t[c*HW + p0];
    float vv[4] = {v.x, v.y, v.z, v.w};
    #pragma unroll
    for (int k = 0; k < 15; ++k) {
      float w = wS[k][c];
      #pragma unroll
      for (int j = 0; j < 4; ++j) acc[k][j] += w * vv[j];
    }
  }
  float obv[3]; for (int i2 = 0; i2 < 3; ++i2) obv[i2] = ob[i2];
  float dbv[12]; for (int i2 = 0; i2 < 12; ++i2) dbv[i2] = db[i2];
  for (int j = 0; j < 4; ++j) {
    int pos = p0 + j;
    long base = (long)n*ATOT + lbase + (long)pos*3;
    #pragma unroll
    for (int a = 0; a < 3; ++a) {
      float lg = acc[a][j] + obv[a];
      comb[(base+a)*5] = lg;
      scores[(long)n*ATOT + lbase + pos*3 + a] = lg;
      #pragma unroll
      for (int q = 0; q < 4; ++q)
        comb[(base+a)*5 + 1 + q] = acc[3 + a*4 + q][j] + dbv[a*4+q];
    }
  }
}

// ---------------- decode ----------------
__device__ void decode_store(int n, int lvl, int idx, int slot,
                             const float* comb, float* cboxes, float* cscores) {
  int W = LW[lvl];
  int a = idx % 3; int p = idx / 3;
  int wx = p % W, hy = p / W;
  double r = (a == 0) ? 0.5 : (a == 1) ? 1.0 : 2.0;
  double sz = (double)LSZ[lvl];
  double wsd = sqrt(sz*sz/r);
  double hsd = wsd * r;
  double cxd = (double)(wx * LSTR[lvl]);
  double cyd = (double)(hy * LSTR[lvl]);
  float ax1 = (float)(cxd - 0.5*wsd), ay1 = (float)(cyd - 0.5*hsd);
  float ax2 = (float)(cxd + 0.5*wsd), ay2 = (float)(cyd + 0.5*hsd);
  float aw = ax2 - ax1, ah = ay2 - ay1;
  float acx = ax1 + 0.5f*aw, acy = ay1 + 0.5f*ah;
  long g = (long)n*ATOT + LBASE[lvl] + idx;
  const float* cm = comb + g*5;
  float sc = cm[0];
  float dx = cm[1], dy = cm[2], dwv = cm[3], dhv = cm[4];
  dwv = fminf(dwv, SCALE_CLAMP); dhv = fminf(dhv, SCALE_CLAMP);
  float pcx = __fadd_rn(__fmul_rn(dx, aw), acx);
  float pcy = __fadd_rn(__fmul_rn(dy, ah), acy);
  float pw = __fmul_rn(expf(dwv), aw);
  float ph = __fmul_rn(expf(dhv), ah);
  float x1 = __fsub_rn(pcx, 0.5f*pw), y1 = __fsub_rn(pcy, 0.5f*ph);
  float x2 = __fadd_rn(pcx, 0.5f*pw), y2 = __fadd_rn(pcy, 0.5f*ph);
  x1 = fminf(fmaxf(x1, 0.f), 1024.f);
  y1 = fminf(fmaxf(y1, 0.f), 1024.f);
  x2 = fminf(fmaxf(x2, 0.f), 1024.f);
  y2 = fminf(fmaxf(y2, 0.f), 1024.f);
  float* cbp = cboxes + ((long)n*MCAND + slot)*4;
  cbp[0]=x1; cbp[1]=y1; cbp[2]=x2; cbp[3]=y2;
  cscores[(long)n*MCAND + slot] = sc;
}

// ---------------- top-k kernels ----------------
__global__ __launch_bounds__(256) void tk_hist(const float* __restrict__ scores,
                                               unsigned* ctl, int pass) {
  int t = blockIdx.y; int lvl = t >> 1, n = t & 1;
  int M = LM[lvl]; long base = (long)n*ATOT + LBASE[lvl];
  __shared__ unsigned h[256];
  h[threadIdx.x] = 0;
  __syncthreads();
  unsigned prefix = ctl[C_PRE + t];
  int shift = 24 - 8*pass;
  for (int i = blockIdx.x*256 + threadIdx.x; i < M; i += gridDim.x*256) {
    unsigned key = fkey(scores[base + i]);
    if (pass == 0 || (key >> (shift+8)) == prefix)
      atomicAdd(&h[(key >> shift) & 255], 1u);
  }
  __syncthreads();
  if (h[threadIdx.x]) atomicAdd(&ctl[C_GH + t*256 + threadIdx.x], h[threadIdx.x]);
}

__global__ __launch_bounds__(256) void tk_pick(unsigned* ctl) {
  int t = blockIdx.x;
  if (threadIdx.x == 0) {
    unsigned kcur = ctl[C_KCUR + t];
    int digit = 0;
    for (int d = 255; d >= 0; --d) {
      unsigned c = ctl[C_GH + t*256 + d];
      if (kcur <= c) { digit = d; break; }
      kcur -= c;
    }
    ctl[C_KCUR + t] = kcur;
    ctl[C_PRE + t] = (ctl[C_PRE + t] << 8) | (unsigned)digit;
  }
  __syncthreads();
  ctl[C_GH + t*256 + threadIdx.x] = 0;
}

__global__ __launch_bounds__(256) void tk_compact(const float* __restrict__ scores,
    const float* __restrict__ comb, unsigned* ctl, float* cboxes, float* cscores) {
  int t = blockIdx.y; int lvl = t >> 1, n = t & 1;
  int M = LM[lvl]; long base = (long)n*ATOT + LBASE[lvl];
  unsigned thr = ctl[C_PRE + t];
  for (int i = blockIdx.x*256 + threadIdx.x; i < M; i += gridDim.x*256) {
    unsigned key = fkey(scores[base + i]);
    if (key > thr) {
      unsigned p = atomicAdd(&ctl[C_CNT + t], 1u);
      if (p < 6000u) decode_store(n, lvl, i, CBASE[lvl] + (int)p, comb, cboxes, cscores);
    } else if (key == thr) {
      unsigned p = atomicAdd(&ctl[C_TIE + t], 1u);
      if (p < 1024u) ctl[C_TIEIDX + t*1024 + p] = (unsigned)i;
    }
  }
}

__global__ void tk_finalize(const float* __restrict__ comb, unsigned* ctl,
                            float* cboxes, float* cscores) {
  int t = blockIdx.x; int lvl = t >> 1, n = t & 1;
  if (threadIdx.x != 0) return;
  int cnt = (int)ctl[C_CNT + t]; if (cnt > 6000) cnt = 6000;
  int need = 6000 - cnt;
  int tc = (int)ctl[C_TIE + t]; if (tc > 1024) tc = 1024;
  unsigned* tb = &ctl[C_TIEIDX + t*1024];
  for (int s = 0; s < need; ++s) {
    unsigned mn = 0xFFFFFFFFu; int mi = -1;
    for (int q = 0; q < tc; ++q) { if (tb[q] < mn) { mn = tb[q]; mi = q; } }
    int slot = CBASE[lvl] + cnt + s;
    if (mi >= 0) {
      tb[mi] = 0xFFFFFFFFu;
      decode_store(n, lvl, (int)mn, slot, comb, cboxes, cscores);
    } else {
      float* cbp = cboxes + ((long)n*MCAND + slot)*4;
      cbp[0]=cbp[1]=cbp[2]=cbp[3]=0.f;
      cscores[(long)n*MCAND + slot] = -3.0e38f;
    }
  }
}

__global__ void decode34(const float* __restrict__ comb, float* cboxes, float* cscores) {
  int n = blockIdx.y;
  int e = blockIdx.x*256 + threadIdx.x;
  if (e >= 3840) return;
  if (e < 3072) decode_store(n, 3, e, 18000 + e, comb, cboxes, cscores);
  else          decode_store(n, 4, e - 3072, 21072 + (e - 3072), comb, cboxes, cscores);
}

// =============== NMS: matrix pipeline ===============
__global__ __launch_bounds__(1024) void nms_select(
    const float* __restrict__ cscores, const float* __restrict__ cboxes,
    float* __restrict__ wt, unsigned* ctl) {
  const int n = blockIdx.x;
  if (ctl[N_DONE + n]) return;
  const int tid = threadIdx.x;
  const float* sc = cscores + (long)n*MCAND;
  const float* cb = cboxes + (long)n*MCAND*4;
  u64* skeyG   = ((u64*)(wt + NS_KEY)) + n*RCAP;
  float* boxO  = wt + NS_BOX + n*RCAP*4;
  float* areaG = wt + NS_AREA + n*RCAP;
  __shared__ u64 skey[RCAP];
  __shared__ unsigned hist[256];
  __shared__ unsigned sS[8];
  unsigned thrPrev = ctl[N_THRPREV + n];
  unsigned prefix = 0, kcur = RCAP;
  for (int pass = 0; pass < 4; ++pass) {
    if (tid < 256) hist[tid] = 0;
    __syncthreads();
    int shift = 24 - 8*pass;
    for (int i = tid; i < MCAND; i += 1024) {
      unsigned key = fkey(sc[i]);
      if (key < thrPrev && (pass == 0 || (key >> (shift+8)) == prefix))
        atomicAdd(&hist[(key >> shift) & 255], 1u);
    }
    __syncthreads();
    if (tid == 0) {
      if (pass == 0) { unsigned s = 0; for (int d = 0; d < 256; ++d) s += hist[d]; sS[2] = s; }
      if (sS[2] > RCAP) {
        unsigned kc = kcur; int digit = 0;
        for (int d = 255; d >= 0; --d) {
          unsigned c = hist[d];
          if (kc <= c) { digit = d; break; }
          kc -= c;
        }
        kcur = kc;
        prefix = (prefix << 8) | (unsigned)digit;
        sS[4] = prefix;
      } else sS[4] = 0;
    }
    __syncthreads();
    prefix = sS[4];
    if (sS[2] <= RCAP) break;
  }
  unsigned thr = (sS[2] <= RCAP) ? 0u : sS[4];
  if (tid == 0) sS[0] = 0;
  for (int i = tid; i < RCAP; i += 1024) skey[i] = 0;
  __syncthreads();
  for (int i = tid; i < MCAND; i += 1024) {
    unsigned key = fkey(sc[i]);
    if (key < thrPrev && key >= thr) {
      unsigned p = atomicAdd(&sS[0], 1u);
      if (p < RCAP) skey[p] = ((u64)key << 32) | (unsigned)(~i);
    }
  }
  __syncthreads();
  unsigned scnt = sS[0] > RCAP ? RCAP : sS[0];
  for (int kk = 2; kk <= RCAP; kk <<= 1) {
    for (int jj = kk >> 1; jj > 0; jj >>= 1) {
      for (int i = tid; i < RCAP; i += 1024) {
        int ixj = i ^ jj;
        if (ixj > i) {
          u64 a = skey[i], b = skey[ixj];
          bool up = ((i & kk) == 0);
          if ((a < b) == up) { skey[i] = b; skey[ixj] = a; }
        }
      }
      __syncthreads();
    }
  }
  for (int s = tid; s < RCAP; s += 1024) {
    u64 v = skey[s];
    skeyG[s] = v;
    float x1=0.f,y1=0.f,x2=0.f,y2=0.f,ar=0.f;
    if (v) {
      int idx = (int)(~(unsigned)v);
      float off = 2000.f * (float)lvl_of(idx);
      x1 = cb[idx*4+0] + off; y1 = cb[idx*4+1] + off;
      x2 = cb[idx*4+2] + off; y2 = cb[idx*4+3] + off;
      ar = (x2-x1)*(y2-y1);
    }
    boxO[s*4+0]=x1; boxO[s*4+1]=y1; boxO[s*4+2]=x2; boxO[s*4+3]=y2;
    areaG[s]=ar;
  }
  if (tid == 0) {
    ctl[N_SCNT + n] = scnt;
    ctl[N_THRPREV + n] = thr;
    if (thr == 0u) ctl[N_LAST + n] = 1;
    if (scnt == 0) ctl[N_DONE + n] = 1;
  }
}

__global__ __launch_bounds__(256) void nms_matrix(const float* __restrict__ wt_c,
                                                  float* __restrict__ wt, unsigned* ctl) {
  const int n = blockIdx.y;
  if (ctl[N_DONE + n]) return;
  const int bx = blockIdx.x;
  const int i0 = bx * 64;
  const int tid = threadIdx.x;
  const int wv = tid >> 6;
  const int lane = tid & 63;
  const float* boxO  = wt_c + NS_BOX + n*RCAP*4;
  const float* areaG = wt_c + NS_AREA + n*RCAP;
  const float* kbox  = wt_c + NS_KBOX + n*1024*5;
  u64* mask  = ((u64*)(wt + NS_MASK)) + (long)n*RCAP*64;
  u64* diagA = ((u64*)(wt + NS_DIAG)) + n*64*64;
  u64* psupW = ((u64*)(wt + NS_PSUP)) + n*64;
  int kt0 = (int)ctl[N_KEPT + n];
  __shared__ float rb[64][5];
  __shared__ unsigned psw[2];
  if (tid < 2) psw[tid] = 0;
  if (tid < 64) {
    rb[tid][0]=boxO[(i0+tid)*4+0]; rb[tid][1]=boxO[(i0+tid)*4+1];
    rb[tid][2]=boxO[(i0+tid)*4+2]; rb[tid][3]=boxO[(i0+tid)*4+3];
    rb[tid][4]=areaG[i0+tid];
  }
  __syncthreads();
  if (kt0 > 0) {
    for (int rr = 0; rr < 16; ++rr) {
      int il = wv*16 + rr;
      float rx1=rb[il][0], ry1=rb[il][1], rx2=rb[il][2], ry2=rb[il][3], rar=rb[il][4];
      bool s = false;
      for (int k = lane; k < kt0; k += 64) {
        float iou = iou_f(rx1,ry1,rx2,ry2,rar,
                          kbox[k*5+0],kbox[k*5+1],kbox[k*5+2],kbox[k*5+3],kbox[k*5+4]);
        s |= (iou > 0.7f);
      }
      u64 bal = __ballot(s);
      if (lane == 0 && bal) atomicOr(&psw[il>>5], 1u << (il & 31));
    }
  }
  __syncthreads();
  if (tid == 0) psupW[bx] = ((u64)psw[1] << 32) | psw[0];
  for (int w = 0; w < 64; ++w) {
    int cidx = w*64 + lane;
    float cx1=boxO[cidx*4+0], cy1=boxO[cidx*4+1], cx2=boxO[cidx*4+2], cy2=boxO[cidx*4+3];
    float car=areaG[cidx];
    #pragma unroll 4
    for (int rr = 0; rr < 16; ++rr) {
      int il = wv*16 + rr;
      int i = i0 + il;
      float iou = iou_f(rb[il][0],rb[il][1],rb[il][2],rb[il][3],rb[il][4],
                        cx1,cy1,cx2,cy2,car);
      bool bit = (iou > 0.7f) && (cidx > i);
      u64 m = __ballot(bit);
      if (lane == 0) {
        mask[(long)i*64 + w] = m;
        if (w == bx) diagA[bx*64 + il] = m;
      }
    }
  }
}

__global__ __launch_bounds__(64) void nms_scan(
    const float* __restrict__ cscores, const float* __restrict__ cboxes,
    float* __restrict__ wt, unsigned* ctl, float* __restrict__ dout) {
  const int n = blockIdx.x;
  if (ctl[N_DONE + n]) return;
  const int lane = threadIdx.x;
  const float* cb = cboxes + (long)n*MCAND*4;
  u64* skeyG = ((u64*)(wt + NS_KEY)) + n*RCAP;
  const float* boxO  = wt + NS_BOX + n*RCAP*4;
  const float* areaG = wt + NS_AREA + n*RCAP;
  u64* mask  = ((u64*)(wt + NS_MASK)) + (long)n*RCAP*64;
  u64* diagA = ((u64*)(wt + NS_DIAG)) + n*64*64;
  u64* psupW = ((u64*)(wt + NS_PSUP)) + n*64;
  float* kbox = wt + NS_KBOX + n*1024*5;
  float* keepB = dout + KB_OFF + (long)n*4*POSTK;
  float* keepS = dout + KS_OFF + (long)n*POSTK;
  float* keepV = dout + KV_OFF + (long)n*POSTK;
  int scnt = (int)ctl[N_SCNT + n];
  int kt = (int)ctl[N_KEPT + n];
  __shared__ u64 alive[64];
  {
    int rem = scnt - lane*64;
    u64 a = rem >= 64 ? ~0ull : (rem > 0 ? ((1ull << rem) - 1ull) : 0ull);
    alive[lane] = a & ~psupW[lane];
  }
  __syncthreads();
  for (int c = 0; c < 64 && kt < POSTK; ++c) {
    u64 w64 = alive[c];
    if (!w64) continue;
    u64 diag = diagA[c*64 + lane];
    u64 kb = 0;
    while (w64) {
      int b = __ffsll(w64) - 1;
      kb |= (1ull << b);
      w64 &= ~(1ull << b);
      u64 sup = __shfl(diag, b);
      w64 &= ~sup;
      if (++kt >= POSTK) break;
    }
    alive[c] = 0;
    if ((kb >> lane) & 1) {
      int base = kt - (int)__popcll(kb);
      int pos = base + (int)__popcll(kb & ((1ull << lane) - 1ull));
      int s = c*64 + lane;
      u64 v = skeyG[s];
      int idx = (int)(~(unsigned)v);
      keepB[pos*4+0]=cb[idx*4+0]; keepB[pos*4+1]=cb[idx*4+1];
      keepB[pos*4+2]=cb[idx*4+2]; keepB[pos*4+3]=cb[idx*4+3];
      keepS[pos] = unfkey((unsigned)(v >> 32));
      keepV[pos] = 1.f;
      kbox[pos*5+0]=boxO[s*4+0]; kbox[pos*5+1]=boxO[s*4+1];
      kbox[pos*5+2]=boxO[s*4+2]; kbox[pos*5+3]=boxO[s*4+3];
      kbox[pos*5+4]=areaG[s];
    }
    __syncthreads();
    if (kb && lane > c && alive[lane]) {
      // 4 independent 16-bit chains -> 4 mask loads in flight (was 1:
      // serial ffs-chain exposed ~200+ cyc L2 latency per kept bit)
      const u64* mrow = mask + (long)c*4096 + lane;
      u64 m0 = kb & 0xFFFFull;
      u64 m1 = (kb >> 16) & 0xFFFFull;
      u64 m2 = (kb >> 32) & 0xFFFFull;
      u64 m3 = (kb >> 48);
      u64 acc = 0;
      while (m0 | m1 | m2 | m3) {
        u64 a0 = 0, a1 = 0, a2 = 0, a3 = 0;
        if (m0) { int b = __ffsll(m0) - 1; m0 &= m0 - 1; a0 = mrow[(long)b*64]; }
        if (m1) { int b = __ffsll(m1) - 1; m1 &= m1 - 1; a1 = mrow[(long)(b+16)*64]; }
        if (m2) { int b = __ffsll(m2) - 1; m2 &= m2 - 1; a2 = mrow[(long)(b+32)*64]; }
        if (m3) { int b = __ffsll(m3) - 1; m3 &= m3 - 1; a3 = mrow[(long)(b+48)*64]; }
        acc |= a0 | a1 | a2 | a3;
      }
      if (acc) alive[lane] &= ~acc;
    }
    __syncthreads();
  }
  if (lane == 0) {
    ctl[N_KEPT + n] = (unsigned)kt;
    if (kt >= POSTK || ctl[N_LAST + n]) ctl[N_DONE + n] = 1;
  }
}

__device__ inline u64 shfl_down_u64d(u64 v, int o) {
  unsigned hi = __shfl_down((unsigned)(v >> 32), o);
  unsigned lo = __shfl_down((unsigned)v, o);
  return ((u64)hi << 32) | lo;
}
__global__ __launch_bounds__(1024) void nms_fill(
    const float* __restrict__ cscores, const float* __restrict__ cboxes,
    unsigned* ctl, float* __restrict__ dout) {
  const int n = blockIdx.x;
  const int tid = threadIdx.x;
  const int lane = tid & 63;
  const int wid = tid >> 6;
  const float* sc = cscores + (long)n*MCAND;
  const float* cb = cboxes + (long)n*MCAND*4;
  float* keepB = dout + KB_OFF + (long)n*4*POSTK;
  float* keepS = dout + KS_OFF + (long)n*POSTK;
  float* keepV = dout + KV_OFF + (long)n*POSTK;
  __shared__ u64 wred[16];
  __shared__ u64 sBest;
  u64 best = 0;
  for (int i = tid; i < 6000; i += 1024) {
    u64 v = ((u64)fkey(sc[i]) << 32) | (unsigned)(~i);
    if (v > best) best = v;
  }
  for (int o = 32; o > 0; o >>= 1) {
    u64 ov = shfl_down_u64d(best, o);
    if (ov > best) best = ov;
  }
  if (lane == 0) wred[wid] = best;
  __syncthreads();
  if (tid == 0) {
    u64 b = 0;
    for (int i = 0; i < 16; ++i) if (wred[i] > b) b = wred[i];
    sBest = b;
  }
  __syncthreads();
  int kt = (int)ctl[N_KEPT + n];
  int bidx = (int)(~(unsigned)sBest);
  float b0 = cb[bidx*4+0], b1 = cb[bidx*4+1], b2 = cb[bidx*4+2], b3 = cb[bidx*4+3];
  float bsc = sc[bidx];
  for (int s2 = kt + tid; s2 < POSTK; s2 += 1024) {
    keepB[s2*4+0]=b0; keepB[s2*4+1]=b1; keepB[s2*4+2]=b2; keepB[s2*4+3]=b3;
    keepS[s2] = bsc; keepV[s2] = 0.f;
  }
}

// ---------------- launcher ----------------
extern "C" void kernel_launch(void* const* d_in, const int* in_sizes, int n_in,
                              void* d_out, int out_size, void* d_ws, size_t ws_size,
                              hipStream_t stream) {
  const float* feats[5];
  for (int i = 0; i < 5; ++i) feats[i] = (const float*)d_in[i];
  const float* conv_w  = (const float*)d_in[5];
  const float* conv_b  = (const float*)d_in[6];
  const float* obj_w   = (const float*)d_in[7];
  const float* obj_b   = (const float*)d_in[8];
  const float* delta_w = (const float*)d_in[9];
  const float* delta_b = (const float*)d_in[10];
  float* out = (float*)d_out;
  float* ws = (float*)d_ws;

  const bool big = ws_size >= (size_t)FT_END * 4ull;
  float *t, *scores, *cboxes, *cscores, *wp;
  unsigned* ctl;
  if (big) {
    t = ws + FT_T; scores = ws + FT_SC; cboxes = ws + FT_CB;
    cscores = ws + FT_CS; ctl = (unsigned*)(ws + FT_CTL); wp = ws + FT_WP;
  } else {
    t = ws + WS_T; scores = ws + WS_SC; cboxes = ws + WS_CB;
    cscores = ws + WS_CS; ctl = (unsigned*)(ws + WS_CTL); wp = ws + WS_WP;
  }

  static const int LWh[5]    = {256,128,64,32,16};
  static const int LBASEh[5] = {0,196608,245760,258048,261120};

  wprep_mfma<<<dim3(2305), dim3(256), 0, stream>>>(conv_w, (f16*)wp, ctl);

  if (big) {
    conv_big<<<dim3(682), dim3(512), 0, stream>>>(
        feats[0], feats[1], feats[2], feats[3], feats[4], (const f16*)wp, conv_b,
        obj_w, obj_b, delta_w, delta_b, out, scores);
  } else {
    for (int n = 0; n < 2; ++n) {
      for (int lvl = 0; lvl < 5; ++lvl) {
        int H = LWh[lvl], W = LWh[lvl], HW = H*W;
        conv_lvl_mfma<<<dim3(W/16, H/8), dim3(256), 0, stream>>>(
            feats[lvl] + (long)n*256*HW, (const f16*)wp, conv_b, t, H, W);
        int hb = (HW + 1023) / 1024;
        heads1x1<<<dim3(hb), dim3(256), 0, stream>>>(
            t, obj_w, obj_b, delta_w, delta_b, out, scores, HW, LBASEh[lvl], n);
      }
    }
  }

  for (int p = 0; p < 4; ++p) {
    tk_hist<<<dim3(48,6), dim3(256), 0, stream>>>(scores, ctl, p);
    tk_pick<<<dim3(6), dim3(256), 0, stream>>>(ctl);
  }
  tk_compact<<<dim3(48,6), dim3(256), 0, stream>>>(scores, out, ctl, cboxes, cscores);
  tk_finalize<<<dim3(6), dim3(64), 0, stream>>>(out, ctl, cboxes, cscores);
  decode34<<<dim3(15,2), dim3(256), 0, stream>>>(out, cboxes, cscores);
  for (int b = 0; b < 6; ++b) {
    nms_select<<<dim3(2), dim3(1024), 0, stream>>>(cscores, cboxes, t, ctl);
    nms_matrix<<<dim3(64,2), dim3(256), 0, stream>>>(t, t, ctl);
    nms_scan<<<dim3(2), dim3(64), 0, stream>>>(cscores, cboxes, t, ctl, out);
  }
  nms_fill<<<dim3(2), dim3(1024), 0, stream>>>(cscores, cboxes, ctl, out);
}